// Round 7
// baseline (371.667 us; speedup 1.0000x reference)
//
#include <hip/hip_runtime.h>

#define NU_N 100000
#define NI_N 50000
#define NN_N 150000          // NU+NI combined nodes
#define E_N  500000
#define NSEL 8192
#define SCAN_BLOCK 256
#define SCAN_ITEMS 1024
#define SCAN_NB ((NN_N + SCAN_ITEMS - 1) / SCAN_ITEMS)   // 147

typedef short s8v __attribute__((ext_vector_type(8)));
typedef short s4v __attribute__((ext_vector_type(4)));
typedef float f4v __attribute__((ext_vector_type(4)));

__device__ __forceinline__ float bf2f(unsigned short h) {
  union { unsigned u; float f; } v; v.u = ((unsigned)h) << 16; return v.f;
}
__device__ __forceinline__ unsigned short f2bf(float f) {
  union { float f; unsigned u; } v; v.f = f;
  unsigned u = v.u;
  u += 0x7FFFu + ((u >> 16) & 1u);   // round-to-nearest-even
  return (unsigned short)(u >> 16);
}

// ---------------- fp32 -> bf16 convert (weights) ----------------
__global__ void k_cvt8(const float* __restrict__ in, unsigned short* __restrict__ out, int n) {
  int t = blockIdx.x * blockDim.x + threadIdx.x;
  int i = t * 8;
  if (i >= n) return;
  float4 a = *(const float4*)(in + i);
  float4 b = *(const float4*)(in + i + 4);
  s8v o;
  o[0] = (short)f2bf(a.x); o[1] = (short)f2bf(a.y);
  o[2] = (short)f2bf(a.z); o[3] = (short)f2bf(a.w);
  o[4] = (short)f2bf(b.x); o[5] = (short)f2bf(b.y);
  o[6] = (short)f2bf(b.z); o[7] = (short)f2bf(b.w);
  *(s8v*)(out + i) = o;
}

// ---------------- fp32 -> bf16 convert producing h and hs = rdeg*h ----------------
__global__ void k_cvt8s(const float* __restrict__ in, unsigned short* __restrict__ h,
                        unsigned short* __restrict__ hs, const float* __restrict__ rdeg, int n) {
  int t = blockIdx.x * blockDim.x + threadIdx.x;
  int i = t * 8;
  if (i >= n) return;
  float rw = rdeg[t >> 3];              // row = i/64 = t/8
  float4 a = *(const float4*)(in + i);
  float4 b = *(const float4*)(in + i + 4);
  s8v o, os;
  o[0] = (short)f2bf(a.x); os[0] = (short)f2bf(a.x * rw);
  o[1] = (short)f2bf(a.y); os[1] = (short)f2bf(a.y * rw);
  o[2] = (short)f2bf(a.z); os[2] = (short)f2bf(a.z * rw);
  o[3] = (short)f2bf(a.w); os[3] = (short)f2bf(a.w * rw);
  o[4] = (short)f2bf(b.x); os[4] = (short)f2bf(b.x * rw);
  o[5] = (short)f2bf(b.y); os[5] = (short)f2bf(b.y * rw);
  o[6] = (short)f2bf(b.z); os[6] = (short)f2bf(b.z * rw);
  o[7] = (short)f2bf(b.w); os[7] = (short)f2bf(b.w * rw);
  *(s8v*)(h + i) = o;
  *(s8v*)(hs + i) = os;
}

// ---------------- degree + per-edge rank (combined node id space) ----------------
__global__ void k_deg(const int* __restrict__ u_idx, const int* __restrict__ i_idx,
                      int* __restrict__ deg, int* __restrict__ rank_u, int* __restrict__ rank_i) {
  int e = blockIdx.x * blockDim.x + threadIdx.x;
  if (e < E_N) {
    rank_u[e] = atomicAdd(deg + u_idx[e], 1);
    rank_i[e] = atomicAdd(deg + NU_N + i_idx[e], 1);
  }
}

__global__ void k_rdeg(const int* __restrict__ deg, float* __restrict__ rdeg) {
  int g = blockIdx.x * blockDim.x + threadIdx.x;
  if (g < NN_N) {
    int d = deg[g];
    rdeg[g] = d > 0 ? 1.0f / sqrtf((float)d) : 0.0f;
  }
}

// ---------------- 3-kernel exclusive scan of deg -> offs ----------------
__global__ void k_scan1(const int* __restrict__ deg, int* __restrict__ offs,
                        int* __restrict__ sums) {
  __shared__ int lds[SCAN_BLOCK];
  int b = blockIdx.x, t = threadIdx.x;
  int base = b * SCAN_ITEMS + t * 4;
  int v[4]; int s = 0;
#pragma unroll
  for (int k = 0; k < 4; k++) {
    int idx = base + k;
    v[k] = idx < NN_N ? deg[idx] : 0;
    s += v[k];
  }
  lds[t] = s;
  __syncthreads();
  for (int off = 1; off < SCAN_BLOCK; off <<= 1) {
    int o = t >= off ? lds[t - off] : 0;
    __syncthreads();
    lds[t] += o;
    __syncthreads();
  }
  int run = lds[t] - s;   // exclusive prefix of this thread
#pragma unroll
  for (int k = 0; k < 4; k++) {
    int idx = base + k;
    if (idx < NN_N) offs[idx] = run;
    run += v[k];
  }
  if (t == SCAN_BLOCK - 1) sums[b] = lds[t];
}

__global__ void k_scan2(int* __restrict__ sums) {
  __shared__ int lds[SCAN_BLOCK];
  int t = threadIdx.x;
  int v = t < SCAN_NB ? sums[t] : 0;
  lds[t] = v;
  __syncthreads();
  for (int off = 1; off < SCAN_BLOCK; off <<= 1) {
    int o = t >= off ? lds[t - off] : 0;
    __syncthreads();
    lds[t] += o;
    __syncthreads();
  }
  if (t < SCAN_NB) sums[t] = lds[t] - v;   // exclusive block base
}

__global__ void k_scan3(int* __restrict__ offs, const int* __restrict__ sums) {
  int idx = blockIdx.x * blockDim.x + threadIdx.x;
  if (idx < NN_N) offs[idx] += sums[idx >> 10];
}

// ---------------- CSR fill + layer-invariant csum accumulation ----------------
// user segments -> nbrU (u16 item ids); item segments -> nbrI (u32 user ids)
// csum_raw[g] += sum over neighbors of rdeg[nb]  (scaled by rdeg[g] in k_update)
__global__ void k_fill(const int* __restrict__ u_idx, const int* __restrict__ i_idx,
                       const int* __restrict__ rank_u, const int* __restrict__ rank_i,
                       const int* __restrict__ offs, const float* __restrict__ rdeg,
                       unsigned short* __restrict__ nbrU, int* __restrict__ nbrI,
                       float* __restrict__ csum) {
  int e = blockIdx.x * blockDim.x + threadIdx.x;
  if (e >= E_N) return;
  int u = u_idx[e], it = i_idx[e];
  int gi = NU_N + it;
  nbrU[offs[u] + rank_u[e]] = (unsigned short)it;
  nbrI[(offs[gi] - E_N) + rank_i[e]] = u;
  atomicAdd(csum + u, rdeg[gi]);
  atomicAdd(csum + gi, rdeg[u]);
}

// ---------------- neighbor gather on pre-scaled table ----------------
// s[g] = rdeg[g] * sum_nb hs[nb]      (hs = rdeg*h, so this equals rdeg[g]*sum rdeg[nb]h[nb])
// 8 neighbor slots/wave; ids preloaded, broadcast via shfl with WAVE-UNIFORM trip
// count (shfl from exited lane undefined -> round-5 bug). Lanes past d hold
// id = NN_N which points at a dedicated always-zero row -> contribute 0.
__global__ void k_gather(const unsigned short* __restrict__ hs,
                         const int* __restrict__ offs, const int* __restrict__ deg,
                         const unsigned short* __restrict__ nbrU, const int* __restrict__ nbrI,
                         const float* __restrict__ rdeg,
                         unsigned short* __restrict__ s) {
  int wid = (blockIdx.x * blockDim.x + threadIdx.x) >> 6;
  if (wid >= NN_N) return;
  int lane = threadIdx.x & 63;
  int q = lane >> 3, m = lane & 7;       // q: neighbor slot, m: 8-bf16 chunk within row
  int d = deg[wid];
  bool isU = wid < NU_N;
  int k0 = isU ? offs[wid] : offs[wid] - E_N;
  int myid = NN_N;                       // zero-row sentinel
  if (lane < d) myid = isU ? (NU_N + (int)nbrU[k0 + lane]) : nbrI[k0 + lane];
  float acc[8] = {0.f, 0.f, 0.f, 0.f, 0.f, 0.f, 0.f, 0.f};
  int dc = d < 64 ? d : 64;
  int niter = (dc + 7) >> 3;             // UNIFORM across the wave
  for (int i = 0; i < niter; i++) {
    int t = (i << 3) + q;                // t <= 63 always
    int nb = __shfl(myid, t);            // NN_N (zero row) when t >= d
    s8v v = *(const s8v*)(hs + (size_t)nb * 64 + m * 8);
#pragma unroll
    for (int j = 0; j < 8; j++) acc[j] += bf2f((unsigned short)v[j]);
  }
  for (int t = 64 + q; t < d; t += 8) {  // fallback (no shfl -> divergence safe)
    int nb = isU ? (NU_N + (int)nbrU[k0 + t]) : nbrI[k0 + t];
    s8v v = *(const s8v*)(hs + (size_t)nb * 64 + m * 8);
#pragma unroll
    for (int j = 0; j < 8; j++) acc[j] += bf2f((unsigned short)v[j]);
  }
#pragma unroll
  for (int off = 8; off < 64; off <<= 1) {
#pragma unroll
    for (int j = 0; j < 8; j++) acc[j] += __shfl_xor(acc[j], off);
  }
  float rw = rdeg[wid];
  if (q == 0) {
    s8v o;
#pragma unroll
    for (int j = 0; j < 8; j++) o[j] = (short)f2bf(acc[j] * rw);
    *(s8v*)(s + (size_t)wid * 64 + m * 8) = o;
  }
}

// ---------------- B-fragment loader (W is 64x64 bf16, row-major [k][n]) ----------------
// mfma_f32_16x16x32_bf16 B layout: n = lane&15, k = 8*(lane>>4)+j
__device__ __forceinline__ void load_bfrags(const unsigned short* __restrict__ wb, s8v bf[4][2]) {
  int lane = threadIdx.x & 63;
  int lm = lane & 15, lq = lane >> 4;
#pragma unroll
  for (int n = 0; n < 4; n++)
#pragma unroll
    for (int kh = 0; kh < 2; kh++) {
      s8v f;
#pragma unroll
      for (int j = 0; j < 8; j++)
        f[j] = (short)wb[(32 * kh + 8 * lq + j) * 64 + 16 * n + lm];
      bf[n][kh] = f;
    }
}

// ---------------- fused node update ----------------
// x = (h+s)@W1 + (1+c)b1 + (h*s)@W2 + c*b2,  c = csum_raw*rdeg
// h = l2norm(leaky(x));  hs = rdeg*h   (for next layer's gather)
__global__ void k_update(unsigned short* __restrict__ h, unsigned short* __restrict__ hs,
                         const unsigned short* __restrict__ s,
                         const float* __restrict__ csum, const float* __restrict__ rdeg,
                         const unsigned short* __restrict__ w1b, const unsigned short* __restrict__ w2b,
                         const float* __restrict__ b1, const float* __restrict__ b2) {
  s8v f1[4][2], f2w[4][2];
  load_bfrags(w1b, f1);
  load_bfrags(w2b, f2w);
  int lane = threadIdx.x & 63;
  int lm = lane & 15, lq = lane >> 4;
  int tile = (blockIdx.x * blockDim.x + threadIdx.x) >> 6;
  if (tile >= NN_N / 16) return;
  int m0 = tile << 4;
  size_t rowo = (size_t)(m0 + lm) * 64;
  s8v h0 = *(const s8v*)(h + rowo + 8 * lq);
  s8v h1 = *(const s8v*)(h + rowo + 32 + 8 * lq);
  s8v s0 = *(const s8v*)(s + rowo + 8 * lq);
  s8v s1 = *(const s8v*)(s + rowo + 32 + 8 * lq);
  s8v a10, a11, a20, a21;
#pragma unroll
  for (int j = 0; j < 8; j++) {
    float hv0 = bf2f((unsigned short)h0[j]), sv0 = bf2f((unsigned short)s0[j]);
    float hv1 = bf2f((unsigned short)h1[j]), sv1 = bf2f((unsigned short)s1[j]);
    a10[j] = (short)f2bf(hv0 + sv0); a20[j] = (short)f2bf(hv0 * sv0);
    a11[j] = (short)f2bf(hv1 + sv1); a21[j] = (short)f2bf(hv1 * sv1);
  }
  f4v c[4];
#pragma unroll
  for (int n = 0; n < 4; n++) c[n] = (f4v){0.f, 0.f, 0.f, 0.f};
#pragma unroll
  for (int n = 0; n < 4; n++) {
    c[n] = __builtin_amdgcn_mfma_f32_16x16x32_bf16(a10, f1[n][0], c[n], 0, 0, 0);
    c[n] = __builtin_amdgcn_mfma_f32_16x16x32_bf16(a11, f1[n][1], c[n], 0, 0, 0);
    c[n] = __builtin_amdgcn_mfma_f32_16x16x32_bf16(a20, f2w[n][0], c[n], 0, 0, 0);
    c[n] = __builtin_amdgcn_mfma_f32_16x16x32_bf16(a21, f2w[n][1], c[n], 0, 0, 0);
  }
  float b1c[4], b2c[4];
#pragma unroll
  for (int n = 0; n < 4; n++) { b1c[n] = b1[16 * n + lm]; b2c[n] = b2[16 * n + lm]; }
  float cm[4], rd[4];
#pragma unroll
  for (int r = 0; r < 4; r++) {
    int row = m0 + 4 * lq + r;
    rd[r] = rdeg[row];
    cm[r] = csum[row] * rd[r];
  }
  float x[4][4], ss[4] = {0.f, 0.f, 0.f, 0.f};
#pragma unroll
  for (int n = 0; n < 4; n++)
#pragma unroll
    for (int r = 0; r < 4; r++) {
      float v = c[n][r] + b1c[n] + cm[r] * (b1c[n] + b2c[n]);
      v = v > 0.0f ? v : 0.2f * v;
      x[n][r] = v;
      ss[r] += v * v;
    }
#pragma unroll
  for (int r = 0; r < 4; r++) {
#pragma unroll
    for (int off = 1; off < 16; off <<= 1) ss[r] += __shfl_xor(ss[r], off);
    ss[r] = 1.0f / fmaxf(sqrtf(ss[r]), 1e-12f);
  }
#pragma unroll
  for (int n = 0; n < 4; n++)
#pragma unroll
    for (int r = 0; r < 4; r++) {
      size_t o = (size_t)(m0 + 4 * lq + r) * 64 + 16 * n + lm;
      float hv = x[n][r] * ss[r];
      h[o]  = f2bf(hv);
      hs[o] = f2bf(hv * rd[r]);
    }
}

// ---------------- output gather for layer slice l (4 cols/thread) ----------------
__global__ void k_out(const float* __restrict__ fu, const float* __restrict__ fi,
                      const unsigned short* __restrict__ h,
                      const int* __restrict__ users, const int* __restrict__ pos,
                      const int* __restrict__ neg, float* __restrict__ out, int l) {
  int t = blockIdx.x * blockDim.x + threadIdx.x;
  if (t >= 3 * NSEL * 16) return;
  int j4 = (t & 15) * 4;
  int row = (t >> 4) & (NSEL - 1);
  int grp = t >> 17;  // 4 + 13
  int sr = grp == 0 ? users[row] : (grp == 1 ? pos[row] : neg[row]);
  float4 v;
  if (l == 0) {
    const float* f = grp == 0 ? fu : fi;
    v = *(const float4*)(f + (size_t)sr * 64 + j4);
  } else {
    const unsigned short* hh = h + (size_t)(grp == 0 ? sr : NU_N + sr) * 64 + j4;
    s4v x = *(const s4v*)hh;
    v.x = bf2f((unsigned short)x[0]); v.y = bf2f((unsigned short)x[1]);
    v.z = bf2f((unsigned short)x[2]); v.w = bf2f((unsigned short)x[3]);
  }
  *(float4*)(out + (size_t)grp * NSEL * 256 + (size_t)row * 256 + (size_t)l * 64 + j4) = v;
}

// ---------------- host launcher ----------------
extern "C" void kernel_launch(void* const* d_in, const int* in_sizes, int n_in,
                              void* d_out, int out_size, void* d_ws, size_t ws_size,
                              hipStream_t stream) {
  (void)in_sizes; (void)n_in; (void)out_size; (void)ws_size;
  const float* fu = (const float*)d_in[0];
  const float* fi = (const float*)d_in[1];
  const float* W1 = (const float*)d_in[2];
  const float* b1 = (const float*)d_in[3];
  const float* W2 = (const float*)d_in[4];
  const float* b2 = (const float*)d_in[5];
  const int* u_idx = (const int*)d_in[6];
  const int* i_idx = (const int*)d_in[7];
  const int* users = (const int*)d_in[8];
  const int* pos   = (const int*)d_in[9];
  const int* neg   = (const int*)d_in[10];
  float* out = (float*)d_out;

  char* w = (char*)d_ws;
  auto alloc = [&](size_t bytes) { char* p = w; w += (bytes + 255) & ~(size_t)255; return p; };
  unsigned short* h  = (unsigned short*)alloc((size_t)NN_N * 64 * 2);       // node embeds
  unsigned short* hs = (unsigned short*)alloc((size_t)(NN_N + 1) * 64 * 2); // rdeg*h (+zero row)
  unsigned short* sb = (unsigned short*)alloc((size_t)NN_N * 64 * 2);       // gathered s
  // deg (int) and csum (float) contiguous -> single memset covers both
  int*   deg  = (int*)alloc((size_t)NN_N * 8);
  float* csum = (float*)(deg + NN_N);
  float* rdeg = (float*)alloc((size_t)NN_N * 4);
  int*   offs = (int*)alloc((size_t)NN_N * 4);
  int*   sums = (int*)alloc((size_t)SCAN_BLOCK * 4);
  int*   rank_u = (int*)alloc((size_t)E_N * 4);
  int*   rank_i = (int*)alloc((size_t)E_N * 4);
  unsigned short* nbrU = (unsigned short*)alloc((size_t)E_N * 2);
  int*   nbrI = (int*)alloc((size_t)E_N * 4);
  unsigned short* w1b = (unsigned short*)alloc((size_t)3 * 4096 * 2);
  unsigned short* w2b = (unsigned short*)alloc((size_t)3 * 4096 * 2);

  // ---- CSR build ----
  hipMemsetAsync(deg, 0, (size_t)NN_N * 8, stream);                 // deg + csum
  hipMemsetAsync(hs + (size_t)NN_N * 64, 0, 128, stream);           // zero sentinel row
  k_deg<<<(E_N + 255) / 256, 256, 0, stream>>>(u_idx, i_idx, deg, rank_u, rank_i);
  k_rdeg<<<(NN_N + 255) / 256, 256, 0, stream>>>(deg, rdeg);
  k_scan1<<<SCAN_NB, SCAN_BLOCK, 0, stream>>>(deg, offs, sums);
  k_scan2<<<1, SCAN_BLOCK, 0, stream>>>(sums);
  k_scan3<<<(NN_N + 255) / 256, 256, 0, stream>>>(offs, sums);
  k_fill<<<(E_N + 255) / 256, 256, 0, stream>>>(u_idx, i_idx, rank_u, rank_i, offs, rdeg,
                                                nbrU, nbrI, csum);

  // ---- bf16 inputs (h and hs = rdeg*h) ----
  k_cvt8s<<<(NU_N * 64 / 8 + 255) / 256, 256, 0, stream>>>(fu, h, hs, rdeg, NU_N * 64);
  k_cvt8s<<<(NI_N * 64 / 8 + 255) / 256, 256, 0, stream>>>(fi, h + (size_t)NU_N * 64,
                                                           hs + (size_t)NU_N * 64,
                                                           rdeg + NU_N, NI_N * 64);
  k_cvt8<<<(3 * 4096 / 8 + 255) / 256, 256, 0, stream>>>(W1, w1b, 3 * 4096);
  k_cvt8<<<(3 * 4096 / 8 + 255) / 256, 256, 0, stream>>>(W2, w2b, 3 * 4096);
  k_out<<<(3 * NSEL * 16 + 255) / 256, 256, 0, stream>>>(fu, fi, h, users, pos, neg, out, 0);

  // ---- layers ----
  for (int l = 0; l < 3; l++) {
    k_gather<<<(NN_N * 64 + 255) / 256, 256, 0, stream>>>(hs, offs, deg, nbrU, nbrI, rdeg, sb);
    k_update<<<((NN_N / 16) * 64 + 255) / 256, 256, 0, stream>>>(
        h, hs, sb, csum, rdeg, w1b + (size_t)l * 4096, w2b + (size_t)l * 4096,
        b1 + (size_t)l * 64, b2 + (size_t)l * 64);
    k_out<<<(3 * NSEL * 16 + 255) / 256, 256, 0, stream>>>(fu, fi, h, users, pos, neg, out, l + 1);
  }
}

// Round 8
// 283.267 us; speedup vs baseline: 1.3121x; 1.3121x over previous
//
#include <hip/hip_runtime.h>

#define NU_N 100000
#define NI_N 50000
#define NN_N 150000          // NU+NI combined nodes
#define E_N  500000
#define NSEL 8192
#define SCAN_BLOCK 256
#define SCAN_ITEMS 1024
#define SCAN_NB ((NN_N + SCAN_ITEMS - 1) / SCAN_ITEMS)   // 147

typedef short s8v __attribute__((ext_vector_type(8)));
typedef short s4v __attribute__((ext_vector_type(4)));
typedef float f4v __attribute__((ext_vector_type(4)));

__device__ __forceinline__ float bf2f(unsigned short h) {
  union { unsigned u; float f; } v; v.u = ((unsigned)h) << 16; return v.f;
}
__device__ __forceinline__ unsigned short f2bf(float f) {
  union { float f; unsigned u; } v; v.f = f;
  unsigned u = v.u;
  u += 0x7FFFu + ((u >> 16) & 1u);   // round-to-nearest-even
  return (unsigned short)(u >> 16);
}

// ---------------- fp32 -> bf16 convert, both weight tensors in one launch ----------------
__global__ void k_cvtW(const float* __restrict__ w1, const float* __restrict__ w2,
                       unsigned short* __restrict__ o1, unsigned short* __restrict__ o2, int n) {
  int t = blockIdx.x * blockDim.x + threadIdx.x;
  int i = t * 8;
  if (i >= n) return;
#pragma unroll
  for (int which = 0; which < 2; which++) {
    const float* in = which ? w2 : w1;
    unsigned short* out = which ? o2 : o1;
    float4 a = *(const float4*)(in + i);
    float4 b = *(const float4*)(in + i + 4);
    s8v o;
    o[0] = (short)f2bf(a.x); o[1] = (short)f2bf(a.y);
    o[2] = (short)f2bf(a.z); o[3] = (short)f2bf(a.w);
    o[4] = (short)f2bf(b.x); o[5] = (short)f2bf(b.y);
    o[6] = (short)f2bf(b.z); o[7] = (short)f2bf(b.w);
    *(s8v*)(out + i) = o;
  }
}

// ---------------- fp32 -> bf16 convert producing h and hs = rdeg*h ----------------
__global__ void k_cvt8s(const float* __restrict__ in, unsigned short* __restrict__ h,
                        unsigned short* __restrict__ hs, const float* __restrict__ rdeg, int n) {
  int t = blockIdx.x * blockDim.x + threadIdx.x;
  int i = t * 8;
  if (i >= n) return;
  float rw = rdeg[t >> 3];              // row = i/64 = t/8
  float4 a = *(const float4*)(in + i);
  float4 b = *(const float4*)(in + i + 4);
  s8v o, os;
  o[0] = (short)f2bf(a.x); os[0] = (short)f2bf(a.x * rw);
  o[1] = (short)f2bf(a.y); os[1] = (short)f2bf(a.y * rw);
  o[2] = (short)f2bf(a.z); os[2] = (short)f2bf(a.z * rw);
  o[3] = (short)f2bf(a.w); os[3] = (short)f2bf(a.w * rw);
  o[4] = (short)f2bf(b.x); os[4] = (short)f2bf(b.x * rw);
  o[5] = (short)f2bf(b.y); os[5] = (short)f2bf(b.y * rw);
  o[6] = (short)f2bf(b.z); os[6] = (short)f2bf(b.z * rw);
  o[7] = (short)f2bf(b.w); os[7] = (short)f2bf(b.w * rw);
  *(s8v*)(h + i) = o;
  *(s8v*)(hs + i) = os;
}

// ---------------- degree + per-edge rank (combined node id space) ----------------
__global__ void k_deg(const int* __restrict__ u_idx, const int* __restrict__ i_idx,
                      int* __restrict__ deg, int* __restrict__ rank_u, int* __restrict__ rank_i) {
  int e = blockIdx.x * blockDim.x + threadIdx.x;
  if (e < E_N) {
    rank_u[e] = atomicAdd(deg + u_idx[e], 1);
    rank_i[e] = atomicAdd(deg + NU_N + i_idx[e], 1);
  }
}

__global__ void k_rdeg(const int* __restrict__ deg, float* __restrict__ rdeg) {
  int g = blockIdx.x * blockDim.x + threadIdx.x;
  if (g < NN_N) {
    int d = deg[g];
    rdeg[g] = d > 0 ? 1.0f / sqrtf((float)d) : 0.0f;
  }
}

// ---------------- 3-kernel exclusive scan of deg -> od = (offs, deg) ----------------
__global__ void k_scan1(const int* __restrict__ deg, int* __restrict__ offs,
                        int* __restrict__ sums) {
  __shared__ int lds[SCAN_BLOCK];
  int b = blockIdx.x, t = threadIdx.x;
  int base = b * SCAN_ITEMS + t * 4;
  int v[4]; int s = 0;
#pragma unroll
  for (int k = 0; k < 4; k++) {
    int idx = base + k;
    v[k] = idx < NN_N ? deg[idx] : 0;
    s += v[k];
  }
  lds[t] = s;
  __syncthreads();
  for (int off = 1; off < SCAN_BLOCK; off <<= 1) {
    int o = t >= off ? lds[t - off] : 0;
    __syncthreads();
    lds[t] += o;
    __syncthreads();
  }
  int run = lds[t] - s;   // exclusive prefix of this thread
#pragma unroll
  for (int k = 0; k < 4; k++) {
    int idx = base + k;
    if (idx < NN_N) offs[idx] = run;
    run += v[k];
  }
  if (t == SCAN_BLOCK - 1) sums[b] = lds[t];
}

__global__ void k_scan2(int* __restrict__ sums) {
  __shared__ int lds[SCAN_BLOCK];
  int t = threadIdx.x;
  int v = t < SCAN_NB ? sums[t] : 0;
  lds[t] = v;
  __syncthreads();
  for (int off = 1; off < SCAN_BLOCK; off <<= 1) {
    int o = t >= off ? lds[t - off] : 0;
    __syncthreads();
    lds[t] += o;
    __syncthreads();
  }
  if (t < SCAN_NB) sums[t] = lds[t] - v;   // exclusive block base
}

__global__ void k_scan3(const int* __restrict__ offs, const int* __restrict__ sums,
                        const int* __restrict__ deg, int2* __restrict__ od) {
  int idx = blockIdx.x * blockDim.x + threadIdx.x;
  if (idx < NN_N) od[idx] = make_int2(offs[idx] + sums[idx >> 10], deg[idx]);
}

// ---------------- CSR fill, atomics-free (rank precomputed) ----------------
// user segments -> nbrU (u16 item ids, slots [0,E)); item segments -> nbrI (u32 user ids)
__global__ void k_fill(const int* __restrict__ u_idx, const int* __restrict__ i_idx,
                       const int* __restrict__ rank_u, const int* __restrict__ rank_i,
                       const int2* __restrict__ od,
                       unsigned short* __restrict__ nbrU, int* __restrict__ nbrI) {
  int e = blockIdx.x * blockDim.x + threadIdx.x;
  if (e >= E_N) return;
  int u = u_idx[e], it = i_idx[e];
  nbrU[od[u].x + rank_u[e]] = (unsigned short)it;
  nbrI[(od[NU_N + it].x - E_N) + rank_i[e]] = u;
}

// ---------------- layer-invariant csum: csum[g] = sum_nb rdeg[nb] (raw, unscaled) ----------------
__global__ void k_csum(const int2* __restrict__ od, const unsigned short* __restrict__ nbrU,
                       const int* __restrict__ nbrI, const float* __restrict__ rdeg,
                       float* __restrict__ csum) {
  int g = blockIdx.x * blockDim.x + threadIdx.x;
  if (g >= NN_N) return;
  int2 o = od[g];
  int d = o.y;
  bool isU = g < NU_N;
  int k0 = isU ? o.x : o.x - E_N;
  float c = 0.0f;
  for (int k = 0; k < d; k++) {
    int nb = isU ? (NU_N + (int)nbrU[k0 + k]) : nbrI[k0 + k];
    c += rdeg[nb];
  }
  csum[g] = c;
}

// ---------------- neighbor gather on pre-scaled table, 2 nodes per wave ----------------
// s[g] = rdeg[g] * sum_nb hs[nb]    (hs = rdeg*h)
// Wave layout: half = lane>>5 selects node (2w+half); within a half, 4 neighbor
// slots x 8 chunk-lanes (16B each) cover one 128B row per slot. Neighbor ids
// preloaded (lane32 < d) and broadcast via shfl with a WAVE-UNIFORM trip count
// (shfl from an exited lane is undefined -> round-5 bug); idle slots hold the
// NN_N zero-row sentinel. d>32 fallback loop is shfl-free (divergence-safe);
// the xor reductions run after reconvergence with all 64 lanes active.
__global__ void k_gather(const unsigned short* __restrict__ hs,
                         const int2* __restrict__ od,
                         const unsigned short* __restrict__ nbrU, const int* __restrict__ nbrI,
                         const float* __restrict__ rdeg,
                         unsigned short* __restrict__ s) {
  int wv = (blockIdx.x * blockDim.x + threadIdx.x) >> 6;
  if (wv >= NN_N / 2) return;
  int lane = threadIdx.x & 63;
  int half = lane >> 5;
  int lane32 = lane & 31;
  int q = lane32 >> 3;                   // slot within half (0..3)
  int m = lane & 7;                      // 16B chunk within row
  int g = wv * 2 + half;
  int2 o = od[g];
  int d = o.y;
  bool isU = g < NU_N;
  int k0 = isU ? o.x : o.x - E_N;
  int myid = NN_N;                       // zero-row sentinel
  if (lane32 < d) myid = isU ? (NU_N + (int)nbrU[k0 + lane32]) : nbrI[k0 + lane32];
  float acc[8] = {0.f, 0.f, 0.f, 0.f, 0.f, 0.f, 0.f, 0.f};
  int dc = d < 32 ? d : 32;
  int nit = (dc + 3) >> 2;               // per-half (uniform within half)
  int nitA = __shfl(nit, 0), nitB = __shfl(nit, 32);
  int niter = nitA > nitB ? nitA : nitB; // UNIFORM across the wave
  for (int i = 0; i < niter; i++) {
    int src = (half << 5) + (i << 2) + q;   // < 64, source lane always active
    int nb = __shfl(myid, src);             // sentinel when slot beyond d
    s8v v = *(const s8v*)(hs + (size_t)nb * 64 + m * 8);
#pragma unroll
    for (int j = 0; j < 8; j++) acc[j] += bf2f((unsigned short)v[j]);
  }
  for (int t = 32 + q; t < d; t += 4) {  // fallback (no shfl -> divergence safe)
    int nb = isU ? (NU_N + (int)nbrU[k0 + t]) : nbrI[k0 + t];
    s8v v = *(const s8v*)(hs + (size_t)nb * 64 + m * 8);
#pragma unroll
    for (int j = 0; j < 8; j++) acc[j] += bf2f((unsigned short)v[j]);
  }
#pragma unroll
  for (int off = 8; off <= 16; off <<= 1) {   // reduce 4 slots within each half
#pragma unroll
    for (int j = 0; j < 8; j++) acc[j] += __shfl_xor(acc[j], off);
  }
  float rw = rdeg[g];
  if (q == 0) {                          // lanes 0-7 (node A) and 32-39 (node B)
    s8v ov;
#pragma unroll
    for (int j = 0; j < 8; j++) ov[j] = (short)f2bf(acc[j] * rw);
    *(s8v*)(s + (size_t)g * 64 + m * 8) = ov;
  }
}

// ---------------- B-fragment loader (W is 64x64 bf16, row-major [k][n]) ----------------
// mfma_f32_16x16x32_bf16 B layout: n = lane&15, k = 8*(lane>>4)+j
__device__ __forceinline__ void load_bfrags(const unsigned short* __restrict__ wb, s8v bf[4][2]) {
  int lane = threadIdx.x & 63;
  int lm = lane & 15, lq = lane >> 4;
#pragma unroll
  for (int n = 0; n < 4; n++)
#pragma unroll
    for (int kh = 0; kh < 2; kh++) {
      s8v f;
#pragma unroll
      for (int j = 0; j < 8; j++)
        f[j] = (short)wb[(32 * kh + 8 * lq + j) * 64 + 16 * n + lm];
      bf[n][kh] = f;
    }
}

// ---------------- fused node update ----------------
// x = (h+s)@W1 + (1+c)b1 + (h*s)@W2 + c*b2,  c = csum_raw*rdeg
// h = l2norm(leaky(x));  hs = rdeg*h   (for next layer's gather)
__global__ void k_update(unsigned short* __restrict__ h, unsigned short* __restrict__ hs,
                         const unsigned short* __restrict__ s,
                         const float* __restrict__ csum, const float* __restrict__ rdeg,
                         const unsigned short* __restrict__ w1b, const unsigned short* __restrict__ w2b,
                         const float* __restrict__ b1, const float* __restrict__ b2) {
  s8v f1[4][2], f2w[4][2];
  load_bfrags(w1b, f1);
  load_bfrags(w2b, f2w);
  int lane = threadIdx.x & 63;
  int lm = lane & 15, lq = lane >> 4;
  int tile = (blockIdx.x * blockDim.x + threadIdx.x) >> 6;
  if (tile >= NN_N / 16) return;
  int m0 = tile << 4;
  size_t rowo = (size_t)(m0 + lm) * 64;
  s8v h0 = *(const s8v*)(h + rowo + 8 * lq);
  s8v h1 = *(const s8v*)(h + rowo + 32 + 8 * lq);
  s8v s0 = *(const s8v*)(s + rowo + 8 * lq);
  s8v s1 = *(const s8v*)(s + rowo + 32 + 8 * lq);
  s8v a10, a11, a20, a21;
#pragma unroll
  for (int j = 0; j < 8; j++) {
    float hv0 = bf2f((unsigned short)h0[j]), sv0 = bf2f((unsigned short)s0[j]);
    float hv1 = bf2f((unsigned short)h1[j]), sv1 = bf2f((unsigned short)s1[j]);
    a10[j] = (short)f2bf(hv0 + sv0); a20[j] = (short)f2bf(hv0 * sv0);
    a11[j] = (short)f2bf(hv1 + sv1); a21[j] = (short)f2bf(hv1 * sv1);
  }
  f4v c[4];
#pragma unroll
  for (int n = 0; n < 4; n++) c[n] = (f4v){0.f, 0.f, 0.f, 0.f};
#pragma unroll
  for (int n = 0; n < 4; n++) {
    c[n] = __builtin_amdgcn_mfma_f32_16x16x32_bf16(a10, f1[n][0], c[n], 0, 0, 0);
    c[n] = __builtin_amdgcn_mfma_f32_16x16x32_bf16(a11, f1[n][1], c[n], 0, 0, 0);
    c[n] = __builtin_amdgcn_mfma_f32_16x16x32_bf16(a20, f2w[n][0], c[n], 0, 0, 0);
    c[n] = __builtin_amdgcn_mfma_f32_16x16x32_bf16(a21, f2w[n][1], c[n], 0, 0, 0);
  }
  float b1c[4], b2c[4];
#pragma unroll
  for (int n = 0; n < 4; n++) { b1c[n] = b1[16 * n + lm]; b2c[n] = b2[16 * n + lm]; }
  float cm[4], rd[4];
#pragma unroll
  for (int r = 0; r < 4; r++) {
    int row = m0 + 4 * lq + r;
    rd[r] = rdeg[row];
    cm[r] = csum[row] * rd[r];
  }
  float x[4][4], ss[4] = {0.f, 0.f, 0.f, 0.f};
#pragma unroll
  for (int n = 0; n < 4; n++)
#pragma unroll
    for (int r = 0; r < 4; r++) {
      float v = c[n][r] + b1c[n] + cm[r] * (b1c[n] + b2c[n]);
      v = v > 0.0f ? v : 0.2f * v;
      x[n][r] = v;
      ss[r] += v * v;
    }
#pragma unroll
  for (int r = 0; r < 4; r++) {
#pragma unroll
    for (int off = 1; off < 16; off <<= 1) ss[r] += __shfl_xor(ss[r], off);
    ss[r] = 1.0f / fmaxf(sqrtf(ss[r]), 1e-12f);
  }
#pragma unroll
  for (int n = 0; n < 4; n++)
#pragma unroll
    for (int r = 0; r < 4; r++) {
      size_t o = (size_t)(m0 + 4 * lq + r) * 64 + 16 * n + lm;
      float hv = x[n][r] * ss[r];
      h[o]  = f2bf(hv);
      hs[o] = f2bf(hv * rd[r]);
    }
}

// ---------------- output gather for layer slice l (4 cols/thread) ----------------
__global__ void k_out(const float* __restrict__ fu, const float* __restrict__ fi,
                      const unsigned short* __restrict__ h,
                      const int* __restrict__ users, const int* __restrict__ pos,
                      const int* __restrict__ neg, float* __restrict__ out, int l) {
  int t = blockIdx.x * blockDim.x + threadIdx.x;
  if (t >= 3 * NSEL * 16) return;
  int j4 = (t & 15) * 4;
  int row = (t >> 4) & (NSEL - 1);
  int grp = t >> 17;  // 4 + 13
  int sr = grp == 0 ? users[row] : (grp == 1 ? pos[row] : neg[row]);
  float4 v;
  if (l == 0) {
    const float* f = grp == 0 ? fu : fi;
    v = *(const float4*)(f + (size_t)sr * 64 + j4);
  } else {
    const unsigned short* hh = h + (size_t)(grp == 0 ? sr : NU_N + sr) * 64 + j4;
    s4v x = *(const s4v*)hh;
    v.x = bf2f((unsigned short)x[0]); v.y = bf2f((unsigned short)x[1]);
    v.z = bf2f((unsigned short)x[2]); v.w = bf2f((unsigned short)x[3]);
  }
  *(float4*)(out + (size_t)grp * NSEL * 256 + (size_t)row * 256 + (size_t)l * 64 + j4) = v;
}

// ---------------- host launcher ----------------
extern "C" void kernel_launch(void* const* d_in, const int* in_sizes, int n_in,
                              void* d_out, int out_size, void* d_ws, size_t ws_size,
                              hipStream_t stream) {
  (void)in_sizes; (void)n_in; (void)out_size; (void)ws_size;
  const float* fu = (const float*)d_in[0];
  const float* fi = (const float*)d_in[1];
  const float* W1 = (const float*)d_in[2];
  const float* b1 = (const float*)d_in[3];
  const float* W2 = (const float*)d_in[4];
  const float* b2 = (const float*)d_in[5];
  const int* u_idx = (const int*)d_in[6];
  const int* i_idx = (const int*)d_in[7];
  const int* users = (const int*)d_in[8];
  const int* pos   = (const int*)d_in[9];
  const int* neg   = (const int*)d_in[10];
  float* out = (float*)d_out;

  char* w = (char*)d_ws;
  auto alloc = [&](size_t bytes) { char* p = w; w += (bytes + 255) & ~(size_t)255; return p; };
  unsigned short* h  = (unsigned short*)alloc((size_t)NN_N * 64 * 2);       // node embeds
  unsigned short* hs = (unsigned short*)alloc((size_t)(NN_N + 1) * 64 * 2); // rdeg*h (+zero row)
  unsigned short* sb = (unsigned short*)alloc((size_t)NN_N * 64 * 2);       // gathered s
  int*   deg  = (int*)alloc((size_t)NN_N * 4);
  float* csum = (float*)alloc((size_t)NN_N * 4);
  float* rdeg = (float*)alloc((size_t)NN_N * 4);
  int*   offs = (int*)alloc((size_t)NN_N * 4);
  int2*  od   = (int2*)alloc((size_t)NN_N * 8);
  int*   sums = (int*)alloc((size_t)SCAN_BLOCK * 4);
  int*   rank_u = (int*)alloc((size_t)E_N * 4);
  int*   rank_i = (int*)alloc((size_t)E_N * 4);
  unsigned short* nbrU = (unsigned short*)alloc((size_t)E_N * 2);
  int*   nbrI = (int*)alloc((size_t)E_N * 4);
  unsigned short* w1b = (unsigned short*)alloc((size_t)3 * 4096 * 2);
  unsigned short* w2b = (unsigned short*)alloc((size_t)3 * 4096 * 2);

  // ---- CSR build ----
  hipMemsetAsync(deg, 0, (size_t)NN_N * 4, stream);
  hipMemsetAsync(hs + (size_t)NN_N * 64, 0, 128, stream);           // zero sentinel row
  k_deg<<<(E_N + 255) / 256, 256, 0, stream>>>(u_idx, i_idx, deg, rank_u, rank_i);
  k_rdeg<<<(NN_N + 255) / 256, 256, 0, stream>>>(deg, rdeg);
  k_scan1<<<SCAN_NB, SCAN_BLOCK, 0, stream>>>(deg, offs, sums);
  k_scan2<<<1, SCAN_BLOCK, 0, stream>>>(sums);
  k_scan3<<<(NN_N + 255) / 256, 256, 0, stream>>>(offs, sums, deg, od);
  k_fill<<<(E_N + 255) / 256, 256, 0, stream>>>(u_idx, i_idx, rank_u, rank_i, od, nbrU, nbrI);
  k_csum<<<(NN_N + 255) / 256, 256, 0, stream>>>(od, nbrU, nbrI, rdeg, csum);

  // ---- bf16 inputs (h and hs = rdeg*h) ----
  k_cvt8s<<<(NU_N * 64 / 8 + 255) / 256, 256, 0, stream>>>(fu, h, hs, rdeg, NU_N * 64);
  k_cvt8s<<<(NI_N * 64 / 8 + 255) / 256, 256, 0, stream>>>(fi, h + (size_t)NU_N * 64,
                                                           hs + (size_t)NU_N * 64,
                                                           rdeg + NU_N, NI_N * 64);
  k_cvtW<<<(3 * 4096 / 8 + 255) / 256, 256, 0, stream>>>(W1, W2, w1b, w2b, 3 * 4096);
  k_out<<<(3 * NSEL * 16 + 255) / 256, 256, 0, stream>>>(fu, fi, h, users, pos, neg, out, 0);

  // ---- layers ----
  for (int l = 0; l < 3; l++) {
    k_gather<<<((NN_N / 2) * 64 + 255) / 256, 256, 0, stream>>>(hs, od, nbrU, nbrI, rdeg, sb);
    k_update<<<((NN_N / 16) * 64 + 255) / 256, 256, 0, stream>>>(
        h, hs, sb, csum, rdeg, w1b + (size_t)l * 4096, w2b + (size_t)l * 4096,
        b1 + (size_t)l * 64, b2 + (size_t)l * 64);
    k_out<<<(3 * NSEL * 16 + 255) / 256, 256, 0, stream>>>(fu, fi, h, users, pos, neg, out, l + 1);
  }
}

// Round 9
// 277.918 us; speedup vs baseline: 1.3373x; 1.0192x over previous
//
#include <hip/hip_runtime.h>

#define NU_N 100000
#define NI_N 50000
#define NN_N 150000          // NU+NI combined nodes
#define E_N  500000
#define NSEL 8192
#define SCAN_BLOCK 256
#define SCAN_ITEMS 1024
#define SCAN_NB ((NN_N + SCAN_ITEMS - 1) / SCAN_ITEMS)   // 147

typedef short s8v __attribute__((ext_vector_type(8)));
typedef short s4v __attribute__((ext_vector_type(4)));
typedef float f4v __attribute__((ext_vector_type(4)));

__device__ __forceinline__ float bf2f(unsigned short h) {
  union { unsigned u; float f; } v; v.u = ((unsigned)h) << 16; return v.f;
}
__device__ __forceinline__ unsigned short f2bf(float f) {
  union { float f; unsigned u; } v; v.f = f;
  unsigned u = v.u;
  u += 0x7FFFu + ((u >> 16) & 1u);   // round-to-nearest-even
  return (unsigned short)(u >> 16);
}

// ---------------- fp32 -> bf16 convert, both weight tensors in one launch ----------------
__global__ void k_cvtW(const float* __restrict__ w1, const float* __restrict__ w2,
                       unsigned short* __restrict__ o1, unsigned short* __restrict__ o2, int n) {
  int t = blockIdx.x * blockDim.x + threadIdx.x;
  int i = t * 8;
  if (i >= n) return;
#pragma unroll
  for (int which = 0; which < 2; which++) {
    const float* in = which ? w2 : w1;
    unsigned short* out = which ? o2 : o1;
    float4 a = *(const float4*)(in + i);
    float4 b = *(const float4*)(in + i + 4);
    s8v o;
    o[0] = (short)f2bf(a.x); o[1] = (short)f2bf(a.y);
    o[2] = (short)f2bf(a.z); o[3] = (short)f2bf(a.w);
    o[4] = (short)f2bf(b.x); o[5] = (short)f2bf(b.y);
    o[6] = (short)f2bf(b.z); o[7] = (short)f2bf(b.w);
    *(s8v*)(out + i) = o;
  }
}

// ---------------- fp32 -> bf16, users+items in one launch, h and hs = rdeg*h ----------------
__global__ void k_cvt8s(const float* __restrict__ fu, const float* __restrict__ fi,
                        unsigned short* __restrict__ h, unsigned short* __restrict__ hs,
                        const float* __restrict__ rdeg) {
  int t = blockIdx.x * blockDim.x + threadIdx.x;
  if (t >= NN_N * 8) return;
  int i = t * 8;
  int row = t >> 3;
  const float* src = row < NU_N ? (fu + i) : (fi + (i - NU_N * 64));
  float rw = rdeg[row];
  float4 a = *(const float4*)(src);
  float4 b = *(const float4*)(src + 4);
  s8v o, os;
  o[0] = (short)f2bf(a.x); os[0] = (short)f2bf(a.x * rw);
  o[1] = (short)f2bf(a.y); os[1] = (short)f2bf(a.y * rw);
  o[2] = (short)f2bf(a.z); os[2] = (short)f2bf(a.z * rw);
  o[3] = (short)f2bf(a.w); os[3] = (short)f2bf(a.w * rw);
  o[4] = (short)f2bf(b.x); os[4] = (short)f2bf(b.x * rw);
  o[5] = (short)f2bf(b.y); os[5] = (short)f2bf(b.y * rw);
  o[6] = (short)f2bf(b.z); os[6] = (short)f2bf(b.z * rw);
  o[7] = (short)f2bf(b.w); os[7] = (short)f2bf(b.w * rw);
  *(s8v*)(h + i) = o;
  *(s8v*)(hs + i) = os;
}

// ---------------- degree (packed u8 x4 per u32) + per-edge rank (u8) ----------------
// deg max ~40 << 255 so the byte-field atomicAdd cannot carry into a neighbor.
__global__ void k_deg(const int* __restrict__ u_idx, const int* __restrict__ i_idx,
                      unsigned* __restrict__ degp,
                      unsigned char* __restrict__ rank_u, unsigned char* __restrict__ rank_i) {
  int e = blockIdx.x * blockDim.x + threadIdx.x;
  if (e >= E_N) return;
  int u = u_idx[e], gi = NU_N + i_idx[e];
  unsigned r1 = atomicAdd(degp + (u >> 2), 1u << (8 * (u & 3)));
  unsigned r2 = atomicAdd(degp + (gi >> 2), 1u << (8 * (gi & 3)));
  rank_u[e] = (unsigned char)(r1 >> (8 * (u & 3)));
  rank_i[e] = (unsigned char)(r2 >> (8 * (gi & 3)));
}

// ---------------- 3-kernel exclusive scan of deg -> od = (offs, deg), rdeg ----------------
__global__ void k_scan1(const unsigned* __restrict__ degp, int* __restrict__ offs,
                        int* __restrict__ sums) {
  __shared__ int lds[SCAN_BLOCK];
  int b = blockIdx.x, t = threadIdx.x;
  int base = b * SCAN_ITEMS + t * 4;            // always 4-aligned; NN_N % 4 == 0
  unsigned wdeg = base < NN_N ? degp[base >> 2] : 0u;
  int v[4]; int s = 0;
#pragma unroll
  for (int k = 0; k < 4; k++) {
    v[k] = (int)((wdeg >> (8 * k)) & 0xFFu);
    s += v[k];
  }
  lds[t] = s;
  __syncthreads();
  for (int off = 1; off < SCAN_BLOCK; off <<= 1) {
    int o = t >= off ? lds[t - off] : 0;
    __syncthreads();
    lds[t] += o;
    __syncthreads();
  }
  int run = lds[t] - s;   // exclusive prefix of this thread
#pragma unroll
  for (int k = 0; k < 4; k++) {
    int idx = base + k;
    if (idx < NN_N) offs[idx] = run;
    run += v[k];
  }
  if (t == SCAN_BLOCK - 1) sums[b] = lds[t];
}

__global__ void k_scan2(int* __restrict__ sums) {
  __shared__ int lds[SCAN_BLOCK];
  int t = threadIdx.x;
  int v = t < SCAN_NB ? sums[t] : 0;
  lds[t] = v;
  __syncthreads();
  for (int off = 1; off < SCAN_BLOCK; off <<= 1) {
    int o = t >= off ? lds[t - off] : 0;
    __syncthreads();
    lds[t] += o;
    __syncthreads();
  }
  if (t < SCAN_NB) sums[t] = lds[t] - v;   // exclusive block base
}

__global__ void k_scan3(const int* __restrict__ offs, const int* __restrict__ sums,
                        const unsigned char* __restrict__ deg8,
                        int2* __restrict__ od, float* __restrict__ rdeg) {
  int idx = blockIdx.x * blockDim.x + threadIdx.x;
  if (idx >= NN_N) return;
  int d = deg8[idx];
  od[idx] = make_int2(offs[idx] + sums[idx >> 10], d);
  rdeg[idx] = d > 0 ? 1.0f / sqrtf((float)d) : 0.0f;
}

// ---------------- CSR fill, atomics-free (rank precomputed) ----------------
// user segments -> nbrU (u16 item ids, slots [0,E)); item segments -> nbrI (u32 user ids)
__global__ void k_fill(const int* __restrict__ u_idx, const int* __restrict__ i_idx,
                       const unsigned char* __restrict__ rank_u,
                       const unsigned char* __restrict__ rank_i,
                       const int2* __restrict__ od,
                       unsigned short* __restrict__ nbrU, int* __restrict__ nbrI) {
  int e = blockIdx.x * blockDim.x + threadIdx.x;
  if (e >= E_N) return;
  int u = u_idx[e], it = i_idx[e];
  nbrU[od[u].x + (int)rank_u[e]] = (unsigned short)it;
  nbrI[(od[NU_N + it].x - E_N) + (int)rank_i[e]] = u;
}

// ---------------- layer-invariant csum: csum[g] = sum_nb rdeg[nb] (raw, unscaled) ----------------
__global__ void k_csum(const int2* __restrict__ od, const unsigned short* __restrict__ nbrU,
                       const int* __restrict__ nbrI, const float* __restrict__ rdeg,
                       float* __restrict__ csum) {
  int g = blockIdx.x * blockDim.x + threadIdx.x;
  if (g >= NN_N) return;
  int2 o = od[g];
  int d = o.y;
  bool isU = g < NU_N;
  int k0 = isU ? o.x : o.x - E_N;
  float c = 0.0f;
  for (int k = 0; k < d; k++) {
    int nb = isU ? (NU_N + (int)nbrU[k0 + k]) : nbrI[k0 + k];
    c += rdeg[nb];
  }
  csum[g] = c;
}

// ---------------- neighbor gather on pre-scaled table, 2 nodes/wave, 16 rows in flight ----------------
// s[g] = rdeg[g] * sum_nb hs[nb]    (hs = rdeg*h)
// Wave layout: half = lane>>5 selects node; within a half, m = lane&7 is the 16B
// chunk, q = (lane&31)>>3 the base slot. Each lane issues FOUR independent row
// loads per iteration (slots q, q+4, q+8, q+12) -> 16 neighbor rows in flight per
// node, niter = ceil(min(d,32)/16) = 1 for ~95% of nodes. Neighbor ids preloaded
// (lane32 < d) and broadcast via shfl with WAVE-UNIFORM trip count (shfl from an
// exited lane is undefined -> round-5 bug); slots >= d hold the NN_N zero-row
// sentinel (L1-resident broadcast, contributes exactly 0). d>32 fallback is
// shfl-free; reductions run after reconvergence.
__global__ void k_gather(const unsigned short* __restrict__ hs,
                         const int2* __restrict__ od,
                         const unsigned short* __restrict__ nbrU, const int* __restrict__ nbrI,
                         const float* __restrict__ rdeg,
                         unsigned short* __restrict__ s) {
  int wv = (blockIdx.x * blockDim.x + threadIdx.x) >> 6;
  if (wv >= NN_N / 2) return;
  int lane = threadIdx.x & 63;
  int half = lane >> 5;
  int lane32 = lane & 31;
  int q = lane32 >> 3;                   // base slot within half (0..3)
  int m = lane & 7;                      // 16B chunk within row
  int g = wv * 2 + half;
  int2 o = od[g];
  int d = o.y;
  bool isU = g < NU_N;
  int k0 = isU ? o.x : o.x - E_N;
  int myid = NN_N;                       // zero-row sentinel
  if (lane32 < d) myid = isU ? (NU_N + (int)nbrU[k0 + lane32]) : nbrI[k0 + lane32];
  float acc[8] = {0.f, 0.f, 0.f, 0.f, 0.f, 0.f, 0.f, 0.f};
  int dc = d < 32 ? d : 32;
  int nit = (dc + 15) >> 4;              // 1 or 2 per half
  int nitA = __shfl(nit, 0), nitB = __shfl(nit, 32);
  int niter = nitA > nitB ? nitA : nitB; // UNIFORM across the wave
  for (int i = 0; i < niter; i++) {
    int b0 = (half << 5) + (i << 4) + q; // slot base; b0+12 <= half*32+31 -> active lane
    int n0 = __shfl(myid, b0);
    int n1 = __shfl(myid, b0 + 4);
    int n2 = __shfl(myid, b0 + 8);
    int n3 = __shfl(myid, b0 + 12);
    s8v v0 = *(const s8v*)(hs + (size_t)n0 * 64 + m * 8);
    s8v v1 = *(const s8v*)(hs + (size_t)n1 * 64 + m * 8);
    s8v v2 = *(const s8v*)(hs + (size_t)n2 * 64 + m * 8);
    s8v v3 = *(const s8v*)(hs + (size_t)n3 * 64 + m * 8);
#pragma unroll
    for (int j = 0; j < 8; j++)
      acc[j] += (bf2f((unsigned short)v0[j]) + bf2f((unsigned short)v1[j])) +
                (bf2f((unsigned short)v2[j]) + bf2f((unsigned short)v3[j]));
  }
  for (int t = 32 + q; t < d; t += 4) {  // fallback (no shfl -> divergence safe)
    int nb = isU ? (NU_N + (int)nbrU[k0 + t]) : nbrI[k0 + t];
    s8v v = *(const s8v*)(hs + (size_t)nb * 64 + m * 8);
#pragma unroll
    for (int j = 0; j < 8; j++) acc[j] += bf2f((unsigned short)v[j]);
  }
#pragma unroll
  for (int off = 8; off <= 16; off <<= 1) {   // reduce 4 base-slots within each half
#pragma unroll
    for (int j = 0; j < 8; j++) acc[j] += __shfl_xor(acc[j], off);
  }
  float rw = rdeg[g];
  if (q == 0) {                          // lanes 0-7 (node A) and 32-39 (node B)
    s8v ov;
#pragma unroll
    for (int j = 0; j < 8; j++) ov[j] = (short)f2bf(acc[j] * rw);
    *(s8v*)(s + (size_t)g * 64 + m * 8) = ov;
  }
}

// ---------------- B-fragment loader (W is 64x64 bf16, row-major [k][n]) ----------------
// mfma_f32_16x16x32_bf16 B layout: n = lane&15, k = 8*(lane>>4)+j
__device__ __forceinline__ void load_bfrags(const unsigned short* __restrict__ wb, s8v bf[4][2]) {
  int lane = threadIdx.x & 63;
  int lm = lane & 15, lq = lane >> 4;
#pragma unroll
  for (int n = 0; n < 4; n++)
#pragma unroll
    for (int kh = 0; kh < 2; kh++) {
      s8v f;
#pragma unroll
      for (int j = 0; j < 8; j++)
        f[j] = (short)wb[(32 * kh + 8 * lq + j) * 64 + 16 * n + lm];
      bf[n][kh] = f;
    }
}

// ---------------- fused node update ----------------
// x = (h+s)@W1 + (1+c)b1 + (h*s)@W2 + c*b2,  c = csum_raw*rdeg
// h = l2norm(leaky(x));  hs = rdeg*h   (for next layer's gather)
__global__ void k_update(unsigned short* __restrict__ h, unsigned short* __restrict__ hs,
                         const unsigned short* __restrict__ s,
                         const float* __restrict__ csum, const float* __restrict__ rdeg,
                         const unsigned short* __restrict__ w1b, const unsigned short* __restrict__ w2b,
                         const float* __restrict__ b1, const float* __restrict__ b2) {
  s8v f1[4][2], f2w[4][2];
  load_bfrags(w1b, f1);
  load_bfrags(w2b, f2w);
  int lane = threadIdx.x & 63;
  int lm = lane & 15, lq = lane >> 4;
  int tile = (blockIdx.x * blockDim.x + threadIdx.x) >> 6;
  if (tile >= NN_N / 16) return;
  int m0 = tile << 4;
  size_t rowo = (size_t)(m0 + lm) * 64;
  s8v h0 = *(const s8v*)(h + rowo + 8 * lq);
  s8v h1 = *(const s8v*)(h + rowo + 32 + 8 * lq);
  s8v s0 = *(const s8v*)(s + rowo + 8 * lq);
  s8v s1 = *(const s8v*)(s + rowo + 32 + 8 * lq);
  s8v a10, a11, a20, a21;
#pragma unroll
  for (int j = 0; j < 8; j++) {
    float hv0 = bf2f((unsigned short)h0[j]), sv0 = bf2f((unsigned short)s0[j]);
    float hv1 = bf2f((unsigned short)h1[j]), sv1 = bf2f((unsigned short)s1[j]);
    a10[j] = (short)f2bf(hv0 + sv0); a20[j] = (short)f2bf(hv0 * sv0);
    a11[j] = (short)f2bf(hv1 + sv1); a21[j] = (short)f2bf(hv1 * sv1);
  }
  f4v c[4];
#pragma unroll
  for (int n = 0; n < 4; n++) c[n] = (f4v){0.f, 0.f, 0.f, 0.f};
#pragma unroll
  for (int n = 0; n < 4; n++) {
    c[n] = __builtin_amdgcn_mfma_f32_16x16x32_bf16(a10, f1[n][0], c[n], 0, 0, 0);
    c[n] = __builtin_amdgcn_mfma_f32_16x16x32_bf16(a11, f1[n][1], c[n], 0, 0, 0);
    c[n] = __builtin_amdgcn_mfma_f32_16x16x32_bf16(a20, f2w[n][0], c[n], 0, 0, 0);
    c[n] = __builtin_amdgcn_mfma_f32_16x16x32_bf16(a21, f2w[n][1], c[n], 0, 0, 0);
  }
  float b1c[4], b2c[4];
#pragma unroll
  for (int n = 0; n < 4; n++) { b1c[n] = b1[16 * n + lm]; b2c[n] = b2[16 * n + lm]; }
  float cm[4], rd[4];
#pragma unroll
  for (int r = 0; r < 4; r++) {
    int row = m0 + 4 * lq + r;
    rd[r] = rdeg[row];
    cm[r] = csum[row] * rd[r];
  }
  float x[4][4], ss[4] = {0.f, 0.f, 0.f, 0.f};
#pragma unroll
  for (int n = 0; n < 4; n++)
#pragma unroll
    for (int r = 0; r < 4; r++) {
      float v = c[n][r] + b1c[n] + cm[r] * (b1c[n] + b2c[n]);
      v = v > 0.0f ? v : 0.2f * v;
      x[n][r] = v;
      ss[r] += v * v;
    }
#pragma unroll
  for (int r = 0; r < 4; r++) {
#pragma unroll
    for (int off = 1; off < 16; off <<= 1) ss[r] += __shfl_xor(ss[r], off);
    ss[r] = 1.0f / fmaxf(sqrtf(ss[r]), 1e-12f);
  }
#pragma unroll
  for (int n = 0; n < 4; n++)
#pragma unroll
    for (int r = 0; r < 4; r++) {
      size_t o = (size_t)(m0 + 4 * lq + r) * 64 + 16 * n + lm;
      float hv = x[n][r] * ss[r];
      h[o]  = f2bf(hv);
      hs[o] = f2bf(hv * rd[r]);
    }
}

// ---------------- output gather for layer slice l (4 cols/thread) ----------------
__global__ void k_out(const float* __restrict__ fu, const float* __restrict__ fi,
                      const unsigned short* __restrict__ h,
                      const int* __restrict__ users, const int* __restrict__ pos,
                      const int* __restrict__ neg, float* __restrict__ out, int l) {
  int t = blockIdx.x * blockDim.x + threadIdx.x;
  if (t >= 3 * NSEL * 16) return;
  int j4 = (t & 15) * 4;
  int row = (t >> 4) & (NSEL - 1);
  int grp = t >> 17;  // 4 + 13
  int sr = grp == 0 ? users[row] : (grp == 1 ? pos[row] : neg[row]);
  float4 v;
  if (l == 0) {
    const float* f = grp == 0 ? fu : fi;
    v = *(const float4*)(f + (size_t)sr * 64 + j4);
  } else {
    const unsigned short* hh = h + (size_t)(grp == 0 ? sr : NU_N + sr) * 64 + j4;
    s4v x = *(const s4v*)hh;
    v.x = bf2f((unsigned short)x[0]); v.y = bf2f((unsigned short)x[1]);
    v.z = bf2f((unsigned short)x[2]); v.w = bf2f((unsigned short)x[3]);
  }
  *(float4*)(out + (size_t)grp * NSEL * 256 + (size_t)row * 256 + (size_t)l * 64 + j4) = v;
}

// ---------------- host launcher ----------------
extern "C" void kernel_launch(void* const* d_in, const int* in_sizes, int n_in,
                              void* d_out, int out_size, void* d_ws, size_t ws_size,
                              hipStream_t stream) {
  (void)in_sizes; (void)n_in; (void)out_size; (void)ws_size;
  const float* fu = (const float*)d_in[0];
  const float* fi = (const float*)d_in[1];
  const float* W1 = (const float*)d_in[2];
  const float* b1 = (const float*)d_in[3];
  const float* W2 = (const float*)d_in[4];
  const float* b2 = (const float*)d_in[5];
  const int* u_idx = (const int*)d_in[6];
  const int* i_idx = (const int*)d_in[7];
  const int* users = (const int*)d_in[8];
  const int* pos   = (const int*)d_in[9];
  const int* neg   = (const int*)d_in[10];
  float* out = (float*)d_out;

  char* w = (char*)d_ws;
  auto alloc = [&](size_t bytes) { char* p = w; w += (bytes + 255) & ~(size_t)255; return p; };
  unsigned short* h  = (unsigned short*)alloc((size_t)NN_N * 64 * 2);       // node embeds
  unsigned short* hs = (unsigned short*)alloc((size_t)(NN_N + 1) * 64 * 2); // rdeg*h (+zero row)
  unsigned short* sb = (unsigned short*)alloc((size_t)NN_N * 64 * 2);       // gathered s
  unsigned* degp = (unsigned*)alloc((size_t)NN_N);                          // u8 x4 packed
  float* csum = (float*)alloc((size_t)NN_N * 4);
  float* rdeg = (float*)alloc((size_t)NN_N * 4);
  int*   offs = (int*)alloc((size_t)NN_N * 4);
  int2*  od   = (int2*)alloc((size_t)NN_N * 8);
  int*   sums = (int*)alloc((size_t)SCAN_BLOCK * 4);
  unsigned char* rank_u = (unsigned char*)alloc((size_t)E_N);
  unsigned char* rank_i = (unsigned char*)alloc((size_t)E_N);
  unsigned short* nbrU = (unsigned short*)alloc((size_t)E_N * 2);
  int*   nbrI = (int*)alloc((size_t)E_N * 4);
  unsigned short* w1b = (unsigned short*)alloc((size_t)3 * 4096 * 2);
  unsigned short* w2b = (unsigned short*)alloc((size_t)3 * 4096 * 2);

  // ---- CSR build ----
  hipMemsetAsync(degp, 0, (size_t)NN_N, stream);
  hipMemsetAsync(hs + (size_t)NN_N * 64, 0, 128, stream);           // zero sentinel row
  k_deg<<<(E_N + 255) / 256, 256, 0, stream>>>(u_idx, i_idx, degp, rank_u, rank_i);
  k_scan1<<<SCAN_NB, SCAN_BLOCK, 0, stream>>>(degp, offs, sums);
  k_scan2<<<1, SCAN_BLOCK, 0, stream>>>(sums);
  k_scan3<<<(NN_N + 255) / 256, 256, 0, stream>>>(offs, sums, (const unsigned char*)degp,
                                                  od, rdeg);
  k_fill<<<(E_N + 255) / 256, 256, 0, stream>>>(u_idx, i_idx, rank_u, rank_i, od, nbrU, nbrI);
  k_csum<<<(NN_N + 255) / 256, 256, 0, stream>>>(od, nbrU, nbrI, rdeg, csum);

  // ---- bf16 inputs (h and hs = rdeg*h) ----
  k_cvt8s<<<(NN_N * 8 + 255) / 256, 256, 0, stream>>>(fu, fi, h, hs, rdeg);
  k_cvtW<<<(3 * 4096 / 8 + 255) / 256, 256, 0, stream>>>(W1, W2, w1b, w2b, 3 * 4096);
  k_out<<<(3 * NSEL * 16 + 255) / 256, 256, 0, stream>>>(fu, fi, h, users, pos, neg, out, 0);

  // ---- layers ----
  for (int l = 0; l < 3; l++) {
    k_gather<<<((NN_N / 2) * 64 + 255) / 256, 256, 0, stream>>>(hs, od, nbrU, nbrI, rdeg, sb);
    k_update<<<((NN_N / 16) * 64 + 255) / 256, 256, 0, stream>>>(
        h, hs, sb, csum, rdeg, w1b + (size_t)l * 4096, w2b + (size_t)l * 4096,
        b1 + (size_t)l * 64, b2 + (size_t)l * 64);
    k_out<<<(3 * NSEL * 16 + 255) / 256, 256, 0, stream>>>(fu, fi, h, users, pos, neg, out, l + 1);
  }
}

// Round 10
// 264.256 us; speedup vs baseline: 1.4065x; 1.0517x over previous
//
#include <hip/hip_runtime.h>

#define NU_N 100000
#define NI_N 50000
#define NN_N 150000          // NU+NI combined nodes
#define E_N  500000
#define NSEL 8192
#define SCAN_BLOCK 256
#define SCAN_ITEMS 1024
#define SCAN_NB ((NN_N + SCAN_ITEMS - 1) / SCAN_ITEMS)   // 147

typedef short s8v __attribute__((ext_vector_type(8)));
typedef short s4v __attribute__((ext_vector_type(4)));
typedef float f4v __attribute__((ext_vector_type(4)));

__device__ __forceinline__ float bf2f(unsigned short h) {
  union { unsigned u; float f; } v; v.u = ((unsigned)h) << 16; return v.f;
}
__device__ __forceinline__ unsigned short f2bf(float f) {
  union { float f; unsigned u; } v; v.f = f;
  unsigned u = v.u;
  u += 0x7FFFu + ((u >> 16) & 1u);   // round-to-nearest-even
  return (unsigned short)(u >> 16);
}

// ---------------- fp32 -> bf16 convert, both weight tensors in one launch ----------------
__global__ void k_cvtW(const float* __restrict__ w1, const float* __restrict__ w2,
                       unsigned short* __restrict__ o1, unsigned short* __restrict__ o2, int n) {
  int t = blockIdx.x * blockDim.x + threadIdx.x;
  int i = t * 8;
  if (i >= n) return;
#pragma unroll
  for (int which = 0; which < 2; which++) {
    const float* in = which ? w2 : w1;
    unsigned short* out = which ? o2 : o1;
    float4 a = *(const float4*)(in + i);
    float4 b = *(const float4*)(in + i + 4);
    s8v o;
    o[0] = (short)f2bf(a.x); o[1] = (short)f2bf(a.y);
    o[2] = (short)f2bf(a.z); o[3] = (short)f2bf(a.w);
    o[4] = (short)f2bf(b.x); o[5] = (short)f2bf(b.y);
    o[6] = (short)f2bf(b.z); o[7] = (short)f2bf(b.w);
    *(s8v*)(out + i) = o;
  }
}

// ---------------- fp32 -> bf16, users+items in one launch, h and hs = rdeg*h ----------------
__global__ void k_cvt8s(const float* __restrict__ fu, const float* __restrict__ fi,
                        unsigned short* __restrict__ h, unsigned short* __restrict__ hs,
                        const float* __restrict__ rdeg) {
  int t = blockIdx.x * blockDim.x + threadIdx.x;
  if (t >= NN_N * 8) return;
  int i = t * 8;
  int row = t >> 3;
  const float* src = row < NU_N ? (fu + i) : (fi + (i - NU_N * 64));
  float rw = rdeg[row];
  float4 a = *(const float4*)(src);
  float4 b = *(const float4*)(src + 4);
  s8v o, os;
  o[0] = (short)f2bf(a.x); os[0] = (short)f2bf(a.x * rw);
  o[1] = (short)f2bf(a.y); os[1] = (short)f2bf(a.y * rw);
  o[2] = (short)f2bf(a.z); os[2] = (short)f2bf(a.z * rw);
  o[3] = (short)f2bf(a.w); os[3] = (short)f2bf(a.w * rw);
  o[4] = (short)f2bf(b.x); os[4] = (short)f2bf(b.x * rw);
  o[5] = (short)f2bf(b.y); os[5] = (short)f2bf(b.y * rw);
  o[6] = (short)f2bf(b.z); os[6] = (short)f2bf(b.z * rw);
  o[7] = (short)f2bf(b.w); os[7] = (short)f2bf(b.w * rw);
  *(s8v*)(h + i) = o;
  *(s8v*)(hs + i) = os;
}

// ---------------- degree (u32 per node -> atomic-throughput floor) + u8 rank ----------------
// Round-9 lesson: packed-u8 counters quadruple contention and LOSE; WRITE_SIZE
// tracks atomic count (~32B/op), not footprint. u32-per-node = 43 us floor.
__global__ void k_deg(const int* __restrict__ u_idx, const int* __restrict__ i_idx,
                      int* __restrict__ deg,
                      unsigned char* __restrict__ rank_u, unsigned char* __restrict__ rank_i) {
  int e = blockIdx.x * blockDim.x + threadIdx.x;
  if (e >= E_N) return;
  rank_u[e] = (unsigned char)atomicAdd(deg + u_idx[e], 1);
  rank_i[e] = (unsigned char)atomicAdd(deg + NU_N + i_idx[e], 1);
}

// ---------------- 3-kernel exclusive scan of deg -> od = (offs, deg), rdeg ----------------
__global__ void k_scan1(const int* __restrict__ deg, int* __restrict__ offs,
                        int* __restrict__ sums) {
  __shared__ int lds[SCAN_BLOCK];
  int b = blockIdx.x, t = threadIdx.x;
  int base = b * SCAN_ITEMS + t * 4;
  int v[4]; int s = 0;
#pragma unroll
  for (int k = 0; k < 4; k++) {
    int idx = base + k;
    v[k] = idx < NN_N ? deg[idx] : 0;
    s += v[k];
  }
  lds[t] = s;
  __syncthreads();
  for (int off = 1; off < SCAN_BLOCK; off <<= 1) {
    int o = t >= off ? lds[t - off] : 0;
    __syncthreads();
    lds[t] += o;
    __syncthreads();
  }
  int run = lds[t] - s;   // exclusive prefix of this thread
#pragma unroll
  for (int k = 0; k < 4; k++) {
    int idx = base + k;
    if (idx < NN_N) offs[idx] = run;
    run += v[k];
  }
  if (t == SCAN_BLOCK - 1) sums[b] = lds[t];
}

__global__ void k_scan2(int* __restrict__ sums) {
  __shared__ int lds[SCAN_BLOCK];
  int t = threadIdx.x;
  int v = t < SCAN_NB ? sums[t] : 0;
  lds[t] = v;
  __syncthreads();
  for (int off = 1; off < SCAN_BLOCK; off <<= 1) {
    int o = t >= off ? lds[t - off] : 0;
    __syncthreads();
    lds[t] += o;
    __syncthreads();
  }
  if (t < SCAN_NB) sums[t] = lds[t] - v;   // exclusive block base
}

__global__ void k_scan3(const int* __restrict__ offs, const int* __restrict__ sums,
                        const int* __restrict__ deg,
                        int2* __restrict__ od, float* __restrict__ rdeg) {
  int idx = blockIdx.x * blockDim.x + threadIdx.x;
  if (idx >= NN_N) return;
  int d = deg[idx];
  od[idx] = make_int2(offs[idx] + sums[idx >> 10], d);
  rdeg[idx] = d > 0 ? 1.0f / sqrtf((float)d) : 0.0f;
}

// ---------------- CSR fill, atomics-free, 4 edges/thread for MLP ----------------
// user segments -> nbrU (u16 item ids, slots [0,E)); item segments -> nbrI (u32 user ids)
__global__ void k_fill(const int* __restrict__ u_idx, const int* __restrict__ i_idx,
                       const unsigned char* __restrict__ rank_u,
                       const unsigned char* __restrict__ rank_i,
                       const int2* __restrict__ od,
                       unsigned short* __restrict__ nbrU, int* __restrict__ nbrI) {
  int t = blockIdx.x * blockDim.x + threadIdx.x;
  if (t >= E_N / 4) return;
  int e = t * 4;
  int4 uu = *(const int4*)(u_idx + e);
  int4 ii = *(const int4*)(i_idx + e);
  uchar4 ru = *(const uchar4*)(rank_u + e);
  uchar4 ri = *(const uchar4*)(rank_i + e);
  int u[4] = {uu.x, uu.y, uu.z, uu.w};
  int it[4] = {ii.x, ii.y, ii.z, ii.w};
  int rua[4] = {ru.x, ru.y, ru.z, ru.w};
  int ria[4] = {ri.x, ri.y, ri.z, ri.w};
  int ou[4], oi[4];
#pragma unroll
  for (int k = 0; k < 4; k++) ou[k] = od[u[k]].x;        // independent gathers
#pragma unroll
  for (int k = 0; k < 4; k++) oi[k] = od[NU_N + it[k]].x;
#pragma unroll
  for (int k = 0; k < 4; k++) {
    nbrU[ou[k] + rua[k]] = (unsigned short)it[k];
    nbrI[(oi[k] - E_N) + ria[k]] = u[k];
  }
}

// ---------------- neighbor gather on pre-scaled table, 2 nodes/wave, 16 rows in flight ----------------
// s[g] = rdeg[g] * sum_nb hs[nb]    (hs = rdeg*h)
// CSUM=1 (layer 0 only): also csum[g] = sum_nb rdeg[nb] (raw) -- layer-invariant,
// consumed by every k_update. Weight loads proven hidden under row-load latency (r6->r7).
// Wave layout: half = lane>>5 selects node; m = lane&7 is the 16B chunk, q =
// (lane&31)>>3 the base slot. Each lane issues FOUR independent row loads per
// iteration -> 16 rows in flight per node; niter = ceil(min(d,32)/16).
// Neighbor ids preloaded (lane32 < d) and broadcast via shfl with WAVE-UNIFORM
// trip count (shfl from an exited lane is undefined -> round-5 bug); slots >= d
// hold the NN_N sentinel (zero hs row, rdeg[NN_N]=0). d>32 fallback is shfl-free.
template <int CSUM>
__global__ void k_gather(const unsigned short* __restrict__ hs,
                         const int2* __restrict__ od,
                         const unsigned short* __restrict__ nbrU, const int* __restrict__ nbrI,
                         const float* __restrict__ rdeg,
                         unsigned short* __restrict__ s, float* __restrict__ csum) {
  int wv = (blockIdx.x * blockDim.x + threadIdx.x) >> 6;
  if (wv >= NN_N / 2) return;
  int lane = threadIdx.x & 63;
  int half = lane >> 5;
  int lane32 = lane & 31;
  int q = lane32 >> 3;                   // base slot within half (0..3)
  int m = lane & 7;                      // 16B chunk within row
  int g = wv * 2 + half;
  int2 o = od[g];
  int d = o.y;
  bool isU = g < NU_N;
  int k0 = isU ? o.x : o.x - E_N;
  int myid = NN_N;                       // sentinel: hs row zero, rdeg 0
  if (lane32 < d) myid = isU ? (NU_N + (int)nbrU[k0 + lane32]) : nbrI[k0 + lane32];
  float myw = 0.0f;
  if (CSUM) myw = rdeg[myid];            // 0 for sentinel
  float acc[8] = {0.f, 0.f, 0.f, 0.f, 0.f, 0.f, 0.f, 0.f};
  float c = 0.f;
  int dc = d < 32 ? d : 32;
  int nit = (dc + 15) >> 4;              // 1 or 2 per half
  int nitA = __shfl(nit, 0), nitB = __shfl(nit, 32);
  int niter = nitA > nitB ? nitA : nitB; // UNIFORM across the wave
  for (int i = 0; i < niter; i++) {
    int b0 = (half << 5) + (i << 4) + q; // b0+12 <= half*32+31 -> source lane active
    int n0 = __shfl(myid, b0);
    int n1 = __shfl(myid, b0 + 4);
    int n2 = __shfl(myid, b0 + 8);
    int n3 = __shfl(myid, b0 + 12);
    if (CSUM) {
      c += __shfl(myw, b0) + __shfl(myw, b0 + 4) +
           __shfl(myw, b0 + 8) + __shfl(myw, b0 + 12);
    }
    s8v v0 = *(const s8v*)(hs + (size_t)n0 * 64 + m * 8);
    s8v v1 = *(const s8v*)(hs + (size_t)n1 * 64 + m * 8);
    s8v v2 = *(const s8v*)(hs + (size_t)n2 * 64 + m * 8);
    s8v v3 = *(const s8v*)(hs + (size_t)n3 * 64 + m * 8);
#pragma unroll
    for (int j = 0; j < 8; j++)
      acc[j] += (bf2f((unsigned short)v0[j]) + bf2f((unsigned short)v1[j])) +
                (bf2f((unsigned short)v2[j]) + bf2f((unsigned short)v3[j]));
  }
  for (int t = 32 + q; t < d; t += 4) {  // fallback (no shfl -> divergence safe)
    int nb = isU ? (NU_N + (int)nbrU[k0 + t]) : nbrI[k0 + t];
    if (CSUM) c += rdeg[nb];
    s8v v = *(const s8v*)(hs + (size_t)nb * 64 + m * 8);
#pragma unroll
    for (int j = 0; j < 8; j++) acc[j] += bf2f((unsigned short)v[j]);
  }
#pragma unroll
  for (int off = 8; off <= 16; off <<= 1) {   // reduce 4 base-slots within each half
#pragma unroll
    for (int j = 0; j < 8; j++) acc[j] += __shfl_xor(acc[j], off);
    if (CSUM) c += __shfl_xor(c, off);
  }
  float rw = rdeg[g];
  if (q == 0) {                          // lanes 0-7 (node A) and 32-39 (node B)
    s8v ov;
#pragma unroll
    for (int j = 0; j < 8; j++) ov[j] = (short)f2bf(acc[j] * rw);
    *(s8v*)(s + (size_t)g * 64 + m * 8) = ov;
    if (CSUM && m == 0) csum[g] = c;     // raw; update scales by rdeg[g]
  }
}

// ---------------- B-fragment loader (W is 64x64 bf16, row-major [k][n]) ----------------
// mfma_f32_16x16x32_bf16 B layout: n = lane&15, k = 8*(lane>>4)+j
__device__ __forceinline__ void load_bfrags(const unsigned short* __restrict__ wb, s8v bf[4][2]) {
  int lane = threadIdx.x & 63;
  int lm = lane & 15, lq = lane >> 4;
#pragma unroll
  for (int n = 0; n < 4; n++)
#pragma unroll
    for (int kh = 0; kh < 2; kh++) {
      s8v f;
#pragma unroll
      for (int j = 0; j < 8; j++)
        f[j] = (short)wb[(32 * kh + 8 * lq + j) * 64 + 16 * n + lm];
      bf[n][kh] = f;
    }
}

// ---------------- fused node update ----------------
// x = (h+s)@W1 + (1+c)b1 + (h*s)@W2 + c*b2,  c = csum_raw*rdeg
// h = l2norm(leaky(x));  hs = rdeg*h   (for next layer's gather)
__global__ void k_update(unsigned short* __restrict__ h, unsigned short* __restrict__ hs,
                         const unsigned short* __restrict__ s,
                         const float* __restrict__ csum, const float* __restrict__ rdeg,
                         const unsigned short* __restrict__ w1b, const unsigned short* __restrict__ w2b,
                         const float* __restrict__ b1, const float* __restrict__ b2) {
  s8v f1[4][2], f2w[4][2];
  load_bfrags(w1b, f1);
  load_bfrags(w2b, f2w);
  int lane = threadIdx.x & 63;
  int lm = lane & 15, lq = lane >> 4;
  int tile = (blockIdx.x * blockDim.x + threadIdx.x) >> 6;
  if (tile >= NN_N / 16) return;
  int m0 = tile << 4;
  size_t rowo = (size_t)(m0 + lm) * 64;
  s8v h0 = *(const s8v*)(h + rowo + 8 * lq);
  s8v h1 = *(const s8v*)(h + rowo + 32 + 8 * lq);
  s8v s0 = *(const s8v*)(s + rowo + 8 * lq);
  s8v s1 = *(const s8v*)(s + rowo + 32 + 8 * lq);
  s8v a10, a11, a20, a21;
#pragma unroll
  for (int j = 0; j < 8; j++) {
    float hv0 = bf2f((unsigned short)h0[j]), sv0 = bf2f((unsigned short)s0[j]);
    float hv1 = bf2f((unsigned short)h1[j]), sv1 = bf2f((unsigned short)s1[j]);
    a10[j] = (short)f2bf(hv0 + sv0); a20[j] = (short)f2bf(hv0 * sv0);
    a11[j] = (short)f2bf(hv1 + sv1); a21[j] = (short)f2bf(hv1 * sv1);
  }
  f4v c[4];
#pragma unroll
  for (int n = 0; n < 4; n++) c[n] = (f4v){0.f, 0.f, 0.f, 0.f};
#pragma unroll
  for (int n = 0; n < 4; n++) {
    c[n] = __builtin_amdgcn_mfma_f32_16x16x32_bf16(a10, f1[n][0], c[n], 0, 0, 0);
    c[n] = __builtin_amdgcn_mfma_f32_16x16x32_bf16(a11, f1[n][1], c[n], 0, 0, 0);
    c[n] = __builtin_amdgcn_mfma_f32_16x16x32_bf16(a20, f2w[n][0], c[n], 0, 0, 0);
    c[n] = __builtin_amdgcn_mfma_f32_16x16x32_bf16(a21, f2w[n][1], c[n], 0, 0, 0);
  }
  float b1c[4], b2c[4];
#pragma unroll
  for (int n = 0; n < 4; n++) { b1c[n] = b1[16 * n + lm]; b2c[n] = b2[16 * n + lm]; }
  float cm[4], rd[4];
#pragma unroll
  for (int r = 0; r < 4; r++) {
    int row = m0 + 4 * lq + r;
    rd[r] = rdeg[row];
    cm[r] = csum[row] * rd[r];
  }
  float x[4][4], ss[4] = {0.f, 0.f, 0.f, 0.f};
#pragma unroll
  for (int n = 0; n < 4; n++)
#pragma unroll
    for (int r = 0; r < 4; r++) {
      float v = c[n][r] + b1c[n] + cm[r] * (b1c[n] + b2c[n]);
      v = v > 0.0f ? v : 0.2f * v;
      x[n][r] = v;
      ss[r] += v * v;
    }
#pragma unroll
  for (int r = 0; r < 4; r++) {
#pragma unroll
    for (int off = 1; off < 16; off <<= 1) ss[r] += __shfl_xor(ss[r], off);
    ss[r] = 1.0f / fmaxf(sqrtf(ss[r]), 1e-12f);
  }
#pragma unroll
  for (int n = 0; n < 4; n++)
#pragma unroll
    for (int r = 0; r < 4; r++) {
      size_t o = (size_t)(m0 + 4 * lq + r) * 64 + 16 * n + lm;
      float hv = x[n][r] * ss[r];
      h[o]  = f2bf(hv);
      hs[o] = f2bf(hv * rd[r]);
    }
}

// ---------------- output gather for layer slice l (4 cols/thread) ----------------
__global__ void k_out(const float* __restrict__ fu, const float* __restrict__ fi,
                      const unsigned short* __restrict__ h,
                      const int* __restrict__ users, const int* __restrict__ pos,
                      const int* __restrict__ neg, float* __restrict__ out, int l) {
  int t = blockIdx.x * blockDim.x + threadIdx.x;
  if (t >= 3 * NSEL * 16) return;
  int j4 = (t & 15) * 4;
  int row = (t >> 4) & (NSEL - 1);
  int grp = t >> 17;  // 4 + 13
  int sr = grp == 0 ? users[row] : (grp == 1 ? pos[row] : neg[row]);
  float4 v;
  if (l == 0) {
    const float* f = grp == 0 ? fu : fi;
    v = *(const float4*)(f + (size_t)sr * 64 + j4);
  } else {
    const unsigned short* hh = h + (size_t)(grp == 0 ? sr : NU_N + sr) * 64 + j4;
    s4v x = *(const s4v*)hh;
    v.x = bf2f((unsigned short)x[0]); v.y = bf2f((unsigned short)x[1]);
    v.z = bf2f((unsigned short)x[2]); v.w = bf2f((unsigned short)x[3]);
  }
  *(float4*)(out + (size_t)grp * NSEL * 256 + (size_t)row * 256 + (size_t)l * 64 + j4) = v;
}

// ---------------- host launcher ----------------
extern "C" void kernel_launch(void* const* d_in, const int* in_sizes, int n_in,
                              void* d_out, int out_size, void* d_ws, size_t ws_size,
                              hipStream_t stream) {
  (void)in_sizes; (void)n_in; (void)out_size; (void)ws_size;
  const float* fu = (const float*)d_in[0];
  const float* fi = (const float*)d_in[1];
  const float* W1 = (const float*)d_in[2];
  const float* b1 = (const float*)d_in[3];
  const float* W2 = (const float*)d_in[4];
  const float* b2 = (const float*)d_in[5];
  const int* u_idx = (const int*)d_in[6];
  const int* i_idx = (const int*)d_in[7];
  const int* users = (const int*)d_in[8];
  const int* pos   = (const int*)d_in[9];
  const int* neg   = (const int*)d_in[10];
  float* out = (float*)d_out;

  char* w = (char*)d_ws;
  auto alloc = [&](size_t bytes) { char* p = w; w += (bytes + 255) & ~(size_t)255; return p; };
  unsigned short* h  = (unsigned short*)alloc((size_t)NN_N * 64 * 2);       // node embeds
  unsigned short* hs = (unsigned short*)alloc((size_t)(NN_N + 1) * 64 * 2); // rdeg*h (+zero row)
  unsigned short* sb = (unsigned short*)alloc((size_t)NN_N * 64 * 2);       // gathered s
  int*   deg  = (int*)alloc((size_t)NN_N * 4);
  float* csum = (float*)alloc((size_t)NN_N * 4);
  float* rdeg = (float*)alloc((size_t)(NN_N + 1) * 4);    // +1: rdeg[NN_N]=0 sentinel
  int*   offs = (int*)alloc((size_t)NN_N * 4);
  int2*  od   = (int2*)alloc((size_t)NN_N * 8);
  int*   sums = (int*)alloc((size_t)SCAN_BLOCK * 4);
  unsigned char* rank_u = (unsigned char*)alloc((size_t)E_N);
  unsigned char* rank_i = (unsigned char*)alloc((size_t)E_N);
  unsigned short* nbrU = (unsigned short*)alloc((size_t)E_N * 2);
  int*   nbrI = (int*)alloc((size_t)E_N * 4);
  unsigned short* w1b = (unsigned short*)alloc((size_t)3 * 4096 * 2);
  unsigned short* w2b = (unsigned short*)alloc((size_t)3 * 4096 * 2);

  // ---- CSR build ----
  hipMemsetAsync(deg, 0, (size_t)NN_N * 4, stream);
  hipMemsetAsync(hs + (size_t)NN_N * 64, 0, 128, stream);           // zero sentinel row
  hipMemsetAsync(rdeg + NN_N, 0, 4, stream);                        // rdeg sentinel
  k_deg<<<(E_N + 255) / 256, 256, 0, stream>>>(u_idx, i_idx, deg, rank_u, rank_i);
  k_scan1<<<SCAN_NB, SCAN_BLOCK, 0, stream>>>(deg, offs, sums);
  k_scan2<<<1, SCAN_BLOCK, 0, stream>>>(sums);
  k_scan3<<<(NN_N + 255) / 256, 256, 0, stream>>>(offs, sums, deg, od, rdeg);
  k_fill<<<(E_N / 4 + 255) / 256, 256, 0, stream>>>(u_idx, i_idx, rank_u, rank_i, od, nbrU, nbrI);

  // ---- bf16 inputs (h and hs = rdeg*h) ----
  k_cvt8s<<<(NN_N * 8 + 255) / 256, 256, 0, stream>>>(fu, fi, h, hs, rdeg);
  k_cvtW<<<(3 * 4096 / 8 + 255) / 256, 256, 0, stream>>>(W1, W2, w1b, w2b, 3 * 4096);
  k_out<<<(3 * NSEL * 16 + 255) / 256, 256, 0, stream>>>(fu, fi, h, users, pos, neg, out, 0);

  // ---- layers ----
  for (int l = 0; l < 3; l++) {
    if (l == 0)
      k_gather<1><<<((NN_N / 2) * 64 + 255) / 256, 256, 0, stream>>>(hs, od, nbrU, nbrI, rdeg,
                                                                     sb, csum);
    else
      k_gather<0><<<((NN_N / 2) * 64 + 255) / 256, 256, 0, stream>>>(hs, od, nbrU, nbrI, rdeg,
                                                                     sb, csum);
    k_update<<<((NN_N / 16) * 64 + 255) / 256, 256, 0, stream>>>(
        h, hs, sb, csum, rdeg, w1b + (size_t)l * 4096, w2b + (size_t)l * 4096,
        b1 + (size_t)l * 64, b2 + (size_t)l * 64);
    k_out<<<(3 * NSEL * 16 + 255) / 256, 256, 0, stream>>>(fu, fi, h, users, pos, neg, out, l + 1);
  }
}

// Round 11
// 256.829 us; speedup vs baseline: 1.4471x; 1.0289x over previous
//
#include <hip/hip_runtime.h>

#define NU_N 100000
#define NI_N 50000
#define NN_N 150000          // NU+NI combined nodes
#define E_N  500000
#define NSEL 8192
#define SCAN_BLOCK 256
#define SCAN_ITEMS 1024
#define SCAN_NB ((NN_N + SCAN_ITEMS - 1) / SCAN_ITEMS)   // 147

typedef short s8v __attribute__((ext_vector_type(8)));
typedef short s4v __attribute__((ext_vector_type(4)));
typedef float f4v __attribute__((ext_vector_type(4)));

__device__ __forceinline__ float bf2f(unsigned short h) {
  union { unsigned u; float f; } v; v.u = ((unsigned)h) << 16; return v.f;
}
__device__ __forceinline__ unsigned short f2bf(float f) {
  union { float f; unsigned u; } v; v.f = f;
  unsigned u = v.u;
  u += 0x7FFFu + ((u >> 16) & 1u);   // round-to-nearest-even
  return (unsigned short)(u >> 16);
}

// ---------------- weights fp32 -> bf16, PRE-SWIZZLED into MFMA B-fragment order ----------------
// frag layout: dst[l*4096 + ((n*2+kh)<<9) + lane*8 + j] = W_l[(32*kh + 8*(lane>>4) + j)*64 + 16*n + (lane&15)]
// so phase-2 loads one b128 per fragment instead of 64 scalar u16 loads.
__global__ void k_cvtW(const float* __restrict__ w1, const float* __restrict__ w2,
                       unsigned short* __restrict__ o1, unsigned short* __restrict__ o2) {
  int t = blockIdx.x * blockDim.x + threadIdx.x;
  if (t >= 3 * 8 * 64) return;
  int lane = t & 63;
  int fk = (t >> 6) & 7;              // (n<<1)|kh
  int l = t >> 9;                     // layer
  int n = fk >> 1, kh = fk & 1;
  int lm = lane & 15, lqq = lane >> 4;
  int dst = l * 4096 + (fk << 9) + (lane << 3);
  s8v v1, v2;
#pragma unroll
  for (int j = 0; j < 8; j++) {
    int src = l * 4096 + (32 * kh + 8 * lqq + j) * 64 + 16 * n + lm;
    v1[j] = (short)f2bf(w1[src]);
    v2[j] = (short)f2bf(w2[src]);
  }
  *(s8v*)(o1 + dst) = v1;
  *(s8v*)(o2 + dst) = v2;
}

// ---------------- fp32 -> bf16, users+items in one launch, h and hs = rdeg*h ----------------
__global__ void k_cvt8s(const float* __restrict__ fu, const float* __restrict__ fi,
                        unsigned short* __restrict__ h, unsigned short* __restrict__ hs,
                        const float* __restrict__ rdeg) {
  int t = blockIdx.x * blockDim.x + threadIdx.x;
  if (t >= NN_N * 8) return;
  int i = t * 8;
  int row = t >> 3;
  const float* src = row < NU_N ? (fu + i) : (fi + (i - NU_N * 64));
  float rw = rdeg[row];
  float4 a = *(const float4*)(src);
  float4 b = *(const float4*)(src + 4);
  s8v o, os;
  o[0] = (short)f2bf(a.x); os[0] = (short)f2bf(a.x * rw);
  o[1] = (short)f2bf(a.y); os[1] = (short)f2bf(a.y * rw);
  o[2] = (short)f2bf(a.z); os[2] = (short)f2bf(a.z * rw);
  o[3] = (short)f2bf(a.w); os[3] = (short)f2bf(a.w * rw);
  o[4] = (short)f2bf(b.x); os[4] = (short)f2bf(b.x * rw);
  o[5] = (short)f2bf(b.y); os[5] = (short)f2bf(b.y * rw);
  o[6] = (short)f2bf(b.z); os[6] = (short)f2bf(b.z * rw);
  o[7] = (short)f2bf(b.w); os[7] = (short)f2bf(b.w * rw);
  *(s8v*)(h + i) = o;
  *(s8v*)(hs + i) = os;
}

// ---------------- degree (u32 per node = atomic-throughput floor) + u8 rank ----------------
// Round-9 lesson: packed-u8 counters quadruple contention and LOSE; WRITE_SIZE
// tracks atomic count (~32B/op), not footprint.
__global__ void k_deg(const int* __restrict__ u_idx, const int* __restrict__ i_idx,
                      int* __restrict__ deg,
                      unsigned char* __restrict__ rank_u, unsigned char* __restrict__ rank_i) {
  int e = blockIdx.x * blockDim.x + threadIdx.x;
  if (e >= E_N) return;
  rank_u[e] = (unsigned char)atomicAdd(deg + u_idx[e], 1);
  rank_i[e] = (unsigned char)atomicAdd(deg + NU_N + i_idx[e], 1);
}

// ---------------- 3-kernel exclusive scan of deg -> od = (offs, deg), rdeg ----------------
__global__ void k_scan1(const int* __restrict__ deg, int* __restrict__ offs,
                        int* __restrict__ sums) {
  __shared__ int lds[SCAN_BLOCK];
  int b = blockIdx.x, t = threadIdx.x;
  int base = b * SCAN_ITEMS + t * 4;
  int v[4]; int s = 0;
#pragma unroll
  for (int k = 0; k < 4; k++) {
    int idx = base + k;
    v[k] = idx < NN_N ? deg[idx] : 0;
    s += v[k];
  }
  lds[t] = s;
  __syncthreads();
  for (int off = 1; off < SCAN_BLOCK; off <<= 1) {
    int o = t >= off ? lds[t - off] : 0;
    __syncthreads();
    lds[t] += o;
    __syncthreads();
  }
  int run = lds[t] - s;   // exclusive prefix of this thread
#pragma unroll
  for (int k = 0; k < 4; k++) {
    int idx = base + k;
    if (idx < NN_N) offs[idx] = run;
    run += v[k];
  }
  if (t == SCAN_BLOCK - 1) sums[b] = lds[t];
}

__global__ void k_scan2(int* __restrict__ sums) {
  __shared__ int lds[SCAN_BLOCK];
  int t = threadIdx.x;
  int v = t < SCAN_NB ? sums[t] : 0;
  lds[t] = v;
  __syncthreads();
  for (int off = 1; off < SCAN_BLOCK; off <<= 1) {
    int o = t >= off ? lds[t - off] : 0;
    __syncthreads();
    lds[t] += o;
    __syncthreads();
  }
  if (t < SCAN_NB) sums[t] = lds[t] - v;   // exclusive block base
}

__global__ void k_scan3(const int* __restrict__ offs, const int* __restrict__ sums,
                        const int* __restrict__ deg,
                        int2* __restrict__ od, float* __restrict__ rdeg) {
  int idx = blockIdx.x * blockDim.x + threadIdx.x;
  if (idx >= NN_N) return;
  int d = deg[idx];
  od[idx] = make_int2(offs[idx] + sums[idx >> 10], d);
  rdeg[idx] = d > 0 ? 1.0f / sqrtf((float)d) : 0.0f;
}

// ---------------- CSR fill, atomics-free, 4 edges/thread for MLP ----------------
__global__ void k_fill(const int* __restrict__ u_idx, const int* __restrict__ i_idx,
                       const unsigned char* __restrict__ rank_u,
                       const unsigned char* __restrict__ rank_i,
                       const int2* __restrict__ od,
                       unsigned short* __restrict__ nbrU, int* __restrict__ nbrI) {
  int t = blockIdx.x * blockDim.x + threadIdx.x;
  if (t >= E_N / 4) return;
  int e = t * 4;
  int4 uu = *(const int4*)(u_idx + e);
  int4 ii = *(const int4*)(i_idx + e);
  uchar4 ru = *(const uchar4*)(rank_u + e);
  uchar4 ri = *(const uchar4*)(rank_i + e);
  int u[4] = {uu.x, uu.y, uu.z, uu.w};
  int it[4] = {ii.x, ii.y, ii.z, ii.w};
  int rua[4] = {ru.x, ru.y, ru.z, ru.w};
  int ria[4] = {ri.x, ri.y, ri.z, ri.w};
  int ou[4], oi[4];
#pragma unroll
  for (int k = 0; k < 4; k++) ou[k] = od[u[k]].x;        // independent gathers
#pragma unroll
  for (int k = 0; k < 4; k++) oi[k] = od[NU_N + it[k]].x;
#pragma unroll
  for (int k = 0; k < 4; k++) {
    nbrU[ou[k] + rua[k]] = (unsigned short)it[k];
    nbrI[(oi[k] - E_N) + ria[k]] = u[k];
  }
}

// ---------------- FUSED gather + node update ----------------
// Block = 512 threads = 8 waves = 16 nodes (one MFMA tile).
// Phase 1 (all 8 waves): wave w gathers nodes m0+2w, m0+2w+1 from hsin
//   (2 nodes/wave, 16 rows in flight; shfl broadcast with WAVE-UNIFORM trip
//   count -- shfl from an exited lane is undefined, round-5 bug; slots >= d hold
//   the NN_N sentinel: zero hs row, rdeg 0). Deposits fp32 s-rows + raw csum in
//   LDS. L0: csum also written to global (layer-invariant, reused by l>0).
// Phase 2 (wave 0 only, after barrier): MFMA update of the 16-row tile.
//   x = (h+s)@W1 + (1+c)b1 + (h*s)@W2 + c*b2; h' = l2norm(leaky(x));
//   writes h (only this block's rows -> no race) and hsout = rdeg*h'
//   (hs double-buffered across layers: other blocks' phase 1 reads hsin).
template <int L0>
__global__ __launch_bounds__(512)
void k_gup(const unsigned short* __restrict__ hsin, unsigned short* __restrict__ hsout,
           unsigned short* __restrict__ h,
           const int2* __restrict__ od,
           const unsigned short* __restrict__ nbrU, const int* __restrict__ nbrI,
           const float* __restrict__ rdeg, float* __restrict__ csum,
           const unsigned short* __restrict__ w1s, const unsigned short* __restrict__ w2s,
           const float* __restrict__ b1, const float* __restrict__ b2) {
  __shared__ float s_lds[16][65];     // +1 pad: phase-2 reads stride 16 rows
  __shared__ float c_lds[16];
  int tid = threadIdx.x;
  int wave = tid >> 6, lane = tid & 63;
  int m0 = blockIdx.x << 4;
  // ---------- phase 1 ----------
  {
    int half = lane >> 5, lane32 = lane & 31;
    int q = lane32 >> 3, m = lane & 7;
    int node = (wave << 1) + half;
    int g = m0 + node;
    int2 o = od[g];
    int d = o.y;
    bool isU = g < NU_N;
    int k0 = isU ? o.x : o.x - E_N;
    int myid = NN_N;                       // sentinel: zero hs row, rdeg 0
    if (lane32 < d) myid = isU ? (NU_N + (int)nbrU[k0 + lane32]) : nbrI[k0 + lane32];
    float myw = 0.0f;
    if (L0) myw = rdeg[myid];
    float acc[8] = {0.f, 0.f, 0.f, 0.f, 0.f, 0.f, 0.f, 0.f};
    float c = 0.f;
    int dc = d < 32 ? d : 32;
    int nit = (dc + 15) >> 4;              // 1 or 2 per half
    int nitA = __shfl(nit, 0), nitB = __shfl(nit, 32);
    int niter = nitA > nitB ? nitA : nitB; // UNIFORM across the wave
    for (int i = 0; i < niter; i++) {
      int b0 = (half << 5) + (i << 4) + q; // source lane always active
      int n0 = __shfl(myid, b0);
      int n1 = __shfl(myid, b0 + 4);
      int n2 = __shfl(myid, b0 + 8);
      int n3 = __shfl(myid, b0 + 12);
      if (L0) {
        c += __shfl(myw, b0) + __shfl(myw, b0 + 4) +
             __shfl(myw, b0 + 8) + __shfl(myw, b0 + 12);
      }
      s8v v0 = *(const s8v*)(hsin + (size_t)n0 * 64 + m * 8);
      s8v v1 = *(const s8v*)(hsin + (size_t)n1 * 64 + m * 8);
      s8v v2 = *(const s8v*)(hsin + (size_t)n2 * 64 + m * 8);
      s8v v3 = *(const s8v*)(hsin + (size_t)n3 * 64 + m * 8);
#pragma unroll
      for (int j = 0; j < 8; j++)
        acc[j] += (bf2f((unsigned short)v0[j]) + bf2f((unsigned short)v1[j])) +
                  (bf2f((unsigned short)v2[j]) + bf2f((unsigned short)v3[j]));
    }
    for (int t = 32 + q; t < d; t += 4) {  // fallback (no shfl -> divergence safe)
      int nb = isU ? (NU_N + (int)nbrU[k0 + t]) : nbrI[k0 + t];
      if (L0) c += rdeg[nb];
      s8v v = *(const s8v*)(hsin + (size_t)nb * 64 + m * 8);
#pragma unroll
      for (int j = 0; j < 8; j++) acc[j] += bf2f((unsigned short)v[j]);
    }
#pragma unroll
    for (int off = 8; off <= 16; off <<= 1) {
#pragma unroll
      for (int j = 0; j < 8; j++) acc[j] += __shfl_xor(acc[j], off);
      if (L0) c += __shfl_xor(c, off);
    }
    float rw = rdeg[g];
    if (q == 0) {                          // lanes 0-7 (node A) / 32-39 (node B)
#pragma unroll
      for (int j = 0; j < 8; j++) s_lds[node][m * 8 + j] = acc[j] * rw;
      if (m == 0) {
        if (L0) { c_lds[node] = c; csum[g] = c; }
        else c_lds[node] = csum[g];
      }
    }
  }
  __syncthreads();
  if (wave) return;
  // ---------- phase 2 (wave 0) ----------
  s8v f1[4][2], f2w[4][2];
#pragma unroll
  for (int n = 0; n < 4; n++)
#pragma unroll
    for (int kh = 0; kh < 2; kh++) {
      int off = (((n << 1) | kh) << 9) + (lane << 3);
      f1[n][kh]  = *(const s8v*)(w1s + off);
      f2w[n][kh] = *(const s8v*)(w2s + off);
    }
  int lm = lane & 15, lq = lane >> 4;
  size_t rowo = (size_t)(m0 + lm) * 64;
  s8v h0 = *(const s8v*)(h + rowo + 8 * lq);
  s8v h1 = *(const s8v*)(h + rowo + 32 + 8 * lq);
  s8v a10, a11, a20, a21;
#pragma unroll
  for (int j = 0; j < 8; j++) {
    float hv0 = bf2f((unsigned short)h0[j]);
    float hv1 = bf2f((unsigned short)h1[j]);
    float sv0 = s_lds[lm][8 * lq + j];
    float sv1 = s_lds[lm][32 + 8 * lq + j];
    a10[j] = (short)f2bf(hv0 + sv0); a20[j] = (short)f2bf(hv0 * sv0);
    a11[j] = (short)f2bf(hv1 + sv1); a21[j] = (short)f2bf(hv1 * sv1);
  }
  f4v cacc[4];
#pragma unroll
  for (int n = 0; n < 4; n++) cacc[n] = (f4v){0.f, 0.f, 0.f, 0.f};
#pragma unroll
  for (int n = 0; n < 4; n++) {
    cacc[n] = __builtin_amdgcn_mfma_f32_16x16x32_bf16(a10, f1[n][0], cacc[n], 0, 0, 0);
    cacc[n] = __builtin_amdgcn_mfma_f32_16x16x32_bf16(a11, f1[n][1], cacc[n], 0, 0, 0);
    cacc[n] = __builtin_amdgcn_mfma_f32_16x16x32_bf16(a20, f2w[n][0], cacc[n], 0, 0, 0);
    cacc[n] = __builtin_amdgcn_mfma_f32_16x16x32_bf16(a21, f2w[n][1], cacc[n], 0, 0, 0);
  }
  float b1c[4], b2c[4];
#pragma unroll
  for (int n = 0; n < 4; n++) { b1c[n] = b1[16 * n + lm]; b2c[n] = b2[16 * n + lm]; }
  float cm[4], rd[4];
#pragma unroll
  for (int r = 0; r < 4; r++) {
    int row = m0 + 4 * lq + r;
    rd[r] = rdeg[row];
    cm[r] = c_lds[4 * lq + r] * rd[r];
  }
  float x[4][4], ss[4] = {0.f, 0.f, 0.f, 0.f};
#pragma unroll
  for (int n = 0; n < 4; n++)
#pragma unroll
    for (int r = 0; r < 4; r++) {
      float v = cacc[n][r] + b1c[n] + cm[r] * (b1c[n] + b2c[n]);
      v = v > 0.0f ? v : 0.2f * v;
      x[n][r] = v;
      ss[r] += v * v;
    }
#pragma unroll
  for (int r = 0; r < 4; r++) {
#pragma unroll
    for (int off = 1; off < 16; off <<= 1) ss[r] += __shfl_xor(ss[r], off);
    ss[r] = 1.0f / fmaxf(sqrtf(ss[r]), 1e-12f);
  }
#pragma unroll
  for (int n = 0; n < 4; n++)
#pragma unroll
    for (int r = 0; r < 4; r++) {
      size_t o = (size_t)(m0 + 4 * lq + r) * 64 + 16 * n + lm;
      float hv = x[n][r] * ss[r];
      h[o]      = f2bf(hv);
      hsout[o]  = f2bf(hv * rd[r]);
    }
}

// ---------------- output gather for layer slice l (4 cols/thread) ----------------
__global__ void k_out(const float* __restrict__ fu, const float* __restrict__ fi,
                      const unsigned short* __restrict__ h,
                      const int* __restrict__ users, const int* __restrict__ pos,
                      const int* __restrict__ neg, float* __restrict__ out, int l) {
  int t = blockIdx.x * blockDim.x + threadIdx.x;
  if (t >= 3 * NSEL * 16) return;
  int j4 = (t & 15) * 4;
  int row = (t >> 4) & (NSEL - 1);
  int grp = t >> 17;  // 4 + 13
  int sr = grp == 0 ? users[row] : (grp == 1 ? pos[row] : neg[row]);
  float4 v;
  if (l == 0) {
    const float* f = grp == 0 ? fu : fi;
    v = *(const float4*)(f + (size_t)sr * 64 + j4);
  } else {
    const unsigned short* hh = h + (size_t)(grp == 0 ? sr : NU_N + sr) * 64 + j4;
    s4v x = *(const s4v*)hh;
    v.x = bf2f((unsigned short)x[0]); v.y = bf2f((unsigned short)x[1]);
    v.z = bf2f((unsigned short)x[2]); v.w = bf2f((unsigned short)x[3]);
  }
  *(float4*)(out + (size_t)grp * NSEL * 256 + (size_t)row * 256 + (size_t)l * 64 + j4) = v;
}

// ---------------- host launcher ----------------
extern "C" void kernel_launch(void* const* d_in, const int* in_sizes, int n_in,
                              void* d_out, int out_size, void* d_ws, size_t ws_size,
                              hipStream_t stream) {
  (void)in_sizes; (void)n_in; (void)out_size; (void)ws_size;
  const float* fu = (const float*)d_in[0];
  const float* fi = (const float*)d_in[1];
  const float* W1 = (const float*)d_in[2];
  const float* b1 = (const float*)d_in[3];
  const float* W2 = (const float*)d_in[4];
  const float* b2 = (const float*)d_in[5];
  const int* u_idx = (const int*)d_in[6];
  const int* i_idx = (const int*)d_in[7];
  const int* users = (const int*)d_in[8];
  const int* pos   = (const int*)d_in[9];
  const int* neg   = (const int*)d_in[10];
  float* out = (float*)d_out;

  char* w = (char*)d_ws;
  auto alloc = [&](size_t bytes) { char* p = w; w += (bytes + 255) & ~(size_t)255; return p; };
  unsigned short* h   = (unsigned short*)alloc((size_t)NN_N * 64 * 2);        // node embeds
  unsigned short* hsA = (unsigned short*)alloc((size_t)(NN_N + 1) * 64 * 2);  // rdeg*h ping
  unsigned short* hsB = (unsigned short*)alloc((size_t)(NN_N + 1) * 64 * 2);  // rdeg*h pong
  int*   deg  = (int*)alloc((size_t)NN_N * 4);
  float* csum = (float*)alloc((size_t)NN_N * 4);
  float* rdeg = (float*)alloc((size_t)(NN_N + 1) * 4);    // +1: rdeg[NN_N]=0 sentinel
  int*   offs = (int*)alloc((size_t)NN_N * 4);
  int2*  od   = (int2*)alloc((size_t)NN_N * 8);
  int*   sums = (int*)alloc((size_t)SCAN_BLOCK * 4);
  unsigned char* rank_u = (unsigned char*)alloc((size_t)E_N);
  unsigned char* rank_i = (unsigned char*)alloc((size_t)E_N);
  unsigned short* nbrU = (unsigned short*)alloc((size_t)E_N * 2);
  int*   nbrI = (int*)alloc((size_t)E_N * 4);
  unsigned short* w1s = (unsigned short*)alloc((size_t)3 * 4096 * 2);
  unsigned short* w2s = (unsigned short*)alloc((size_t)3 * 4096 * 2);

  // ---- CSR build ----
  hipMemsetAsync(deg, 0, (size_t)NN_N * 4, stream);
  hipMemsetAsync(hsA + (size_t)NN_N * 64, 0, 128, stream);          // zero sentinel rows
  hipMemsetAsync(hsB + (size_t)NN_N * 64, 0, 128, stream);
  hipMemsetAsync(rdeg + NN_N, 0, 4, stream);                        // rdeg sentinel
  k_deg<<<(E_N + 255) / 256, 256, 0, stream>>>(u_idx, i_idx, deg, rank_u, rank_i);
  k_scan1<<<SCAN_NB, SCAN_BLOCK, 0, stream>>>(deg, offs, sums);
  k_scan2<<<1, SCAN_BLOCK, 0, stream>>>(sums);
  k_scan3<<<(NN_N + 255) / 256, 256, 0, stream>>>(offs, sums, deg, od, rdeg);
  k_fill<<<(E_N / 4 + 255) / 256, 256, 0, stream>>>(u_idx, i_idx, rank_u, rank_i, od, nbrU, nbrI);

  // ---- bf16 inputs ----
  k_cvt8s<<<(NN_N * 8 + 255) / 256, 256, 0, stream>>>(fu, fi, h, hsA, rdeg);
  k_cvtW<<<(3 * 8 * 64 + 255) / 256, 256, 0, stream>>>(W1, W2, w1s, w2s);
  k_out<<<(3 * NSEL * 16 + 255) / 256, 256, 0, stream>>>(fu, fi, h, users, pos, neg, out, 0);

  // ---- layers (fused gather+update; hs ping-pong) ----
  unsigned short* hin = hsA;
  unsigned short* hout = hsB;
  for (int l = 0; l < 3; l++) {
    if (l == 0)
      k_gup<1><<<NN_N / 16, 512, 0, stream>>>(hin, hout, h, od, nbrU, nbrI, rdeg, csum,
                                              w1s + (size_t)l * 4096, w2s + (size_t)l * 4096,
                                              b1 + (size_t)l * 64, b2 + (size_t)l * 64);
    else
      k_gup<0><<<NN_N / 16, 512, 0, stream>>>(hin, hout, h, od, nbrU, nbrI, rdeg, csum,
                                              w1s + (size_t)l * 4096, w2s + (size_t)l * 4096,
                                              b1 + (size_t)l * 64, b2 + (size_t)l * 64);
    k_out<<<(3 * NSEL * 16 + 255) / 256, 256, 0, stream>>>(fu, fi, h, users, pos, neg, out, l + 1);
    unsigned short* tmp = hin; hin = hout; hout = tmp;
  }
}